// Round 5
// baseline (303.390 us; speedup 1.0000x reference)
//
#include <hip/hip_runtime.h>
#include <math.h>

#define PI_F 3.14159265358979323846f

constexpr int Bq = 8, Lq = 1024, Sq = 1024, Hq = 8, Dq = 64;

typedef short short8 __attribute__((ext_vector_type(8)));
typedef float f4v __attribute__((ext_vector_type(4)));
typedef unsigned short ushort_t;

static __device__ __forceinline__ ushort_t f2bf(float x) {
  union { float f; unsigned u; } v; v.f = x;
  unsigned r = v.u + 0x7fffu + ((v.u >> 16) & 1u);   // RNE
  return (ushort_t)(r >> 16);
}
static __device__ __forceinline__ float bf2f(ushort_t b) {
  union { unsigned u; float f; } v; v.u = ((unsigned)b) << 16;
  return v.f;
}
static __device__ __forceinline__ f4v mfma16(short8 a, short8 b, f4v c) {
  return __builtin_amdgcn_mfma_f32_16x16x32_bf16(a, b, c, 0, 0, 0);
}
// q~' from q~: pairs (re,im) -> (im,-re); bf16 negate = sign-bit flip
static __device__ __forceinline__ short8 primef(short8 q) {
  short8 r;
#pragma unroll
  for (int i = 0; i < 4; ++i) {
    r[2 * i]     = q[2 * i + 1];
    r[2 * i + 1] = (short)(((ushort_t)q[2 * i]) ^ 0x8000u);
  }
  return r;
}

// ---------------------------------------------------------------------------
// state-math: angles -> diag -> WHT -> st[32] interleaved (re,im) f32
// ---------------------------------------------------------------------------
static __device__ __forceinline__ void state_vec(
    const float* __restrict__ x, const float lw[4][64], const float lb[4],
    int n, float st[32])
{
  const float4* xp = (const float4*)(x + (size_t)n * 64);
  float a0 = lb[0], a1 = lb[1], a2 = lb[2], a3 = lb[3];
#pragma unroll
  for (int i = 0; i < 16; ++i) {
    float4 v = xp[i];
    a0 += v.x * lw[0][4*i] + v.y * lw[0][4*i+1] + v.z * lw[0][4*i+2] + v.w * lw[0][4*i+3];
    a1 += v.x * lw[1][4*i] + v.y * lw[1][4*i+1] + v.z * lw[1][4*i+2] + v.w * lw[1][4*i+3];
    a2 += v.x * lw[2][4*i] + v.y * lw[2][4*i+1] + v.z * lw[2][4*i+2] + v.w * lw[2][4*i+3];
    a3 += v.x * lw[3][4*i] + v.y * lw[3][4*i+1] + v.z * lw[3][4*i+2] + v.w * lw[3][4*i+3];
  }
  a0 = tanhf(a0) * PI_F; a1 = tanhf(a1) * PI_F;
  a2 = tanhf(a2) * PI_F; a3 = tanhf(a3) * PI_F;
  float p01 = a0 * a1, p12 = a1 * a2, p23 = a2 * a3;

  float dr[16], di[16];
#pragma unroll
  for (int d = 0; d < 16; ++d) {
    float s0 = (d & 8) ? -1.f : 1.f;
    float s1 = (d & 4) ? -1.f : 1.f;
    float s2 = (d & 2) ? -1.f : 1.f;
    float s3 = (d & 1) ? -1.f : 1.f;
    float arg = a0*s0 + a1*s1 + a2*s2 + a3*s3
              + p01*s0*s1 + p12*s1*s2 + p23*s2*s3;
    float sn, cs;
    sincosf(0.5f * arg, &sn, &cs);
    dr[d] = cs; di[d] = -sn;
  }
  float hr[16], hi[16];
#pragma unroll
  for (int i = 0; i < 16; ++i) { hr[i] = dr[i]; hi[i] = di[i]; }
#pragma unroll
  for (int stp = 1; stp < 16; stp <<= 1) {
#pragma unroll
    for (int i = 0; i < 16; ++i) {
      if (!(i & stp)) {
        float xr = hr[i], yr = hr[i + stp];
        hr[i] = xr + yr; hr[i + stp] = xr - yr;
        float xi = hi[i], yi = hi[i + stp];
        hi[i] = xi + yi; hi[i + stp] = xi - yi;
      }
    }
  }
#pragma unroll
  for (int d = 0; d < 16; ++d) {
    st[2*d]   = (dr[d] * hr[d] - di[d] * hi[d]) * 0.0625f;
    st[2*d+1] = (dr[d] * hi[d] + di[d] * hr[d]) * 0.0625f;
  }
}

static __device__ __forceinline__ void pack_store(
    const float st[32], ushort_t* __restrict__ outH,
    ushort_t* __restrict__ outL, size_t rb)
{
  unsigned uh[16], ul[16];
#pragma unroll
  for (int d = 0; d < 16; ++d) {
    ushort_t rh = f2bf(st[2*d]), ih = f2bf(st[2*d+1]);
    ushort_t rl = f2bf(st[2*d]   - bf2f(rh));
    ushort_t il = f2bf(st[2*d+1] - bf2f(ih));
    uh[d] = (unsigned)rh | ((unsigned)ih << 16);
    ul[d] = (unsigned)rl | ((unsigned)il << 16);
  }
  uint4* ph = (uint4*)(outH + rb);
  uint4* pl = (uint4*)(outL + rb);
#pragma unroll
  for (int i = 0; i < 4; ++i) {
    ph[i] = make_uint4(uh[4*i], uh[4*i+1], uh[4*i+2], uh[4*i+3]);
    pl[i] = make_uint4(ul[4*i], ul[4*i+1], ul[4*i+2], ul[4*i+3]);
  }
}

// ---------------------------------------------------------------------------
// k_states2: states as bf16 hi/lo.  [(b*8+h)*1024 + l][32].
// ---------------------------------------------------------------------------
__global__ __launch_bounds__(256) void k_states2(
    const float* __restrict__ x, const float* __restrict__ w,
    const float* __restrict__ bias, ushort_t* __restrict__ outH,
    ushort_t* __restrict__ outL)
{
  __shared__ float lw[4][64];
  __shared__ float lb[4];
  int t = threadIdx.x;
  lw[t >> 6][t & 63] = w[t];
  if (t < 4) lb[t] = bias[t];
  __syncthreads();

  int n = blockIdx.x * 256 + t;
  float st[32];
  state_vec(x, lw, lb, n, st);
  int b = n >> 13, l = (n >> 3) & 1023, h = n & 7;
  pack_store(st, outH, outL, ((size_t)(b * Hq + h) * Lq + l) * 32);
}

// ---------------------------------------------------------------------------
// k_vt: V [B][S][H][64] f32  ->  VT [bh][d][s] bf16 hi/lo (transposed per bh)
// ---------------------------------------------------------------------------
__global__ __launch_bounds__(256) void k_vt(
    const float* __restrict__ v, ushort_t* __restrict__ vtH,
    ushort_t* __restrict__ vtL)
{
  __shared__ float tile[64 * 68];
  int bid = blockIdx.x;
  int bh = bid >> 4, s0 = (bid & 15) << 6;
  int b = bh >> 3, h = bh & 7;
  int t = threadIdx.x;
  int sl = t >> 2, dq = (t & 3) << 4;
  const float4* src = (const float4*)(v + (((size_t)b * Sq + s0 + sl) * Hq + h) * 64 + dq);
#pragma unroll
  for (int i = 0; i < 4; ++i)
    *(float4*)&tile[sl * 68 + dq + 4 * i] = src[i];
  __syncthreads();
  int d = t >> 2, sq = (t & 3) << 4;
  unsigned hw[8], lw2[8];
#pragma unroll
  for (int j = 0; j < 8; ++j) {
    float x0 = tile[(sq + 2*j)     * 68 + d];
    float x1 = tile[(sq + 2*j + 1) * 68 + d];
    ushort_t h0 = f2bf(x0), h1 = f2bf(x1);
    ushort_t l0 = f2bf(x0 - bf2f(h0)), l1 = f2bf(x1 - bf2f(h1));
    hw[j]  = (unsigned)h0 | ((unsigned)h1 << 16);
    lw2[j] = (unsigned)l0 | ((unsigned)l1 << 16);
  }
  size_t ob = ((size_t)bh * 64 + d) * 1024 + s0 + sq;
  uint4* oh = (uint4*)(vtH + ob);
  uint4* ol = (uint4*)(vtL + ob);
  oh[0] = make_uint4(hw[0], hw[1], hw[2], hw[3]);
  oh[1] = make_uint4(hw[4], hw[5], hw[6], hw[7]);
  ol[0] = make_uint4(lw2[0], lw2[1], lw2[2], lw2[3]);
  ol[1] = make_uint4(lw2[4], lw2[5], lw2[6], lw2[7]);
}

// ---------------------------------------------------------------------------
// k_fid: normalized attention scores, nothing else.
// 1024 blocks (bh, 64-row tile), 4 waves x 16 rows, full 1024 s per wave.
// Pass 1: hi-only fid -> rowsum (in-register, full row per wave).
// Pass 2 per 64-s chunk: split-3 fid -> scale -> per-wave LDS transpose
//        -> coalesced 256-B row-segment stores.
// ---------------------------------------------------------------------------
__global__ __launch_bounds__(256) void k_fid(
    const ushort_t* __restrict__ QH, const ushort_t* __restrict__ QL,
    const ushort_t* __restrict__ KH, const ushort_t* __restrict__ KL,
    float* __restrict__ attn)
{
  __shared__ float Wtr[4][16 * 68];

  int bid = blockIdx.x;                 // 1024 (%8==0 -> bijective swizzle)
  int xcd = bid & 7, idx = bid >> 3;
  int bh = (xcd << 3) | (idx >> 4);
  int l0 = (idx & 15) << 6;
  int t = threadIdx.x;
  int wv = t >> 6, lane = t & 63;
  int lh = lane & 15, g = lane >> 4, ko = g << 3;
  int rowbase = l0 + (wv << 4);

  size_t qoff = ((size_t)bh * Lq + rowbase + lh) * 32 + ko;
  short8 qh  = *(const short8*)(QH + qoff);
  short8 ql  = *(const short8*)(QL + qoff);
  short8 qph = primef(qh), qpl = primef(ql);

  const ushort_t* kbh = KH + ((size_t)bh * Sq + lh) * 32 + ko;
  const ushort_t* kbl = KL + ((size_t)bh * Sq + lh) * 32 + ko;

  f4v zero = {0.f, 0.f, 0.f, 0.f};

  // ---- pass 1: rowsum, hi-only fid ----
  float rsum = 0.f;
  for (int sf = 0; sf < 64; ++sf) {
    short8 kh = *(const short8*)(kbh + sf * 512);
    f4v fr = mfma16(kh, qh, zero);
    f4v fi = mfma16(kh, qph, zero);
#pragma unroll
    for (int r = 0; r < 4; ++r) rsum += fr[r]*fr[r] + fi[r]*fi[r];
  }
  rsum += __shfl_xor(rsum, 16);
  rsum += __shfl_xor(rsum, 32);
  float rinv = 1.f / (rsum + 1e-6f);

  // ---- pass 2: split-3 fid -> normalize -> transpose -> store ----
  float* abase = attn + ((size_t)bh * Lq + rowbase) * Sq;
  float* wtr = &Wtr[wv][0];

  for (int c = 0; c < 16; ++c) {
    int coff = c * 2048;                // (c*64)*32
#pragma unroll
    for (int f = 0; f < 4; ++f) {
      short8 kh = *(const short8*)(kbh + coff + f * 512);
      short8 kl = *(const short8*)(kbl + coff + f * 512);
      f4v fr = mfma16(kh, qh, zero);
      fr = mfma16(kl, qh, fr);
      fr = mfma16(kh, ql, fr);
      f4v fi = mfma16(kh, qph, zero);
      fi = mfma16(kl, qph, fi);
      fi = mfma16(kh, qpl, fi);
      f4v wv4;
#pragma unroll
      for (int r = 0; r < 4; ++r)
        wv4[r] = (fr[r]*fr[r] + fi[r]*fi[r]) * rinv;
      *(f4v*)&wtr[lh * 68 + (f << 4) + (g << 2)] = wv4;
    }
    // per-wave transpose readback -> coalesced stores (4 rows x 256 B each)
#pragma unroll
    for (int j = 0; j < 4; ++j) {
      int rowp = (j << 2) + g;
      f4v vv = *(const f4v*)&wtr[rowp * 68 + (lh << 2)];
      *(f4v*)(abase + (size_t)rowp * Sq + (c << 6) + (lh << 2)) = vv;
    }
  }
}

// ---------------------------------------------------------------------------
// k_pv: ctx = attn . V   (per bh: [1024 x 1024] x [1024 x 64], K=1024)
// 1024 blocks (bh, 64-row tile), 4 waves x 16 rows.
// A = attn f32 rows, split to bf16 hi/lo inline; B = VT bf16 hi/lo.
// ---------------------------------------------------------------------------
__global__ __launch_bounds__(256) void k_pv(
    const float* __restrict__ attn, const ushort_t* __restrict__ VTH,
    const ushort_t* __restrict__ VTL, float* __restrict__ ctx)
{
  int bid = blockIdx.x;                 // 1024
  int xcd = bid & 7, idx = bid >> 3;
  int bh = (xcd << 3) | (idx >> 4);
  int l0 = (idx & 15) << 6;
  int t = threadIdx.x;
  int wv = t >> 6, lane = t & 63;
  int lh = lane & 15, g = lane >> 4;
  int rowbase = l0 + (wv << 4);

  const float* arow = attn + ((size_t)bh * Lq + rowbase + lh) * Sq + (g << 3);
  const ushort_t* vh0 = VTH + ((size_t)bh * 64 + lh) * Sq + (g << 3);
  const ushort_t* vl0 = VTL + ((size_t)bh * 64 + lh) * Sq + (g << 3);

  f4v zero = {0.f, 0.f, 0.f, 0.f};
  f4v acc[4] = {zero, zero, zero, zero};

  float4 a0 = *(const float4*)(arow);
  float4 a1 = *(const float4*)(arow + 4);

  for (int s0 = 0; s0 < 1024; s0 += 32) {
    float4 na0, na1;
    if (s0 < 992) {
      na0 = *(const float4*)(arow + s0 + 32);
      na1 = *(const float4*)(arow + s0 + 36);
    }
    // issue B loads early
    short8 vh[4], vl[4];
#pragma unroll
    for (int f2 = 0; f2 < 4; ++f2) {
      vh[f2] = *(const short8*)(vh0 + (size_t)(f2 << 4) * Sq + s0);
      vl[f2] = *(const short8*)(vl0 + (size_t)(f2 << 4) * Sq + s0);
    }
    // convert A (8 f32) -> hi/lo bf16
    float av[8] = {a0.x, a0.y, a0.z, a0.w, a1.x, a1.y, a1.z, a1.w};
    short8 wh, wl;
#pragma unroll
    for (int e = 0; e < 8; ++e) {
      union { float f; unsigned u; } cv; cv.f = av[e];
      unsigned tu = cv.u & 0xFFFF0000u;
      union { unsigned u; float f; } hv; hv.u = tu;
      wh[e] = (short)(tu >> 16);
      wl[e] = (short)f2bf(av[e] - hv.f);
    }
#pragma unroll
    for (int f2 = 0; f2 < 4; ++f2) {
      acc[f2] = mfma16(wh, vh[f2], acc[f2]);
      acc[f2] = mfma16(wl, vh[f2], acc[f2]);
      acc[f2] = mfma16(wh, vl[f2], acc[f2]);
    }
    a0 = na0; a1 = na1;
  }

  int b = bh >> 3, h = bh & 7;
#pragma unroll
  for (int f2 = 0; f2 < 4; ++f2) {
    int d = (f2 << 4) + lh;
#pragma unroll
    for (int r = 0; r < 4; ++r) {
      int l = rowbase + (g << 2) + r;
      ctx[(((size_t)b * Lq + l) * Hq + h) * 64 + d] = acc[f2][r];
    }
  }
}

// ===========================================================================
extern "C" void kernel_launch(void* const* d_in, const int* in_sizes, int n_in,
                              void* d_out, int out_size, void* d_ws, size_t ws_size,
                              hipStream_t stream) {
  const float* q  = (const float*)d_in[0];
  const float* k  = (const float*)d_in[1];
  const float* v  = (const float*)d_in[2];
  const float* wq = (const float*)d_in[3];
  const float* bq = (const float*)d_in[4];
  const float* wk = (const float*)d_in[5];
  const float* bk = (const float*)d_in[6];

  float* out  = (float*)d_out;
  float* ctx  = out;                    // [B,L,H,D]  = 4,194,304 floats
  float* attn = out + 4194304;          // [B,H,L,S]  = 67,108,864 floats

  char* wsb = (char*)d_ws;
  ushort_t* QH  = (ushort_t*)(wsb);
  ushort_t* QL  = (ushort_t*)(wsb + (size_t)4  * 1024 * 1024);
  ushort_t* KH  = (ushort_t*)(wsb + (size_t)8  * 1024 * 1024);
  ushort_t* KL  = (ushort_t*)(wsb + (size_t)12 * 1024 * 1024);
  ushort_t* VTH = (ushort_t*)(wsb + (size_t)16 * 1024 * 1024);
  ushort_t* VTL = (ushort_t*)(wsb + (size_t)24 * 1024 * 1024);

  hipLaunchKernelGGL(k_states2, dim3(256), dim3(256), 0, stream, q, wq, bq, QH, QL);
  hipLaunchKernelGGL(k_states2, dim3(256), dim3(256), 0, stream, k, wk, bk, KH, KL);
  hipLaunchKernelGGL(k_vt, dim3(1024), dim3(256), 0, stream, v, VTH, VTL);
  hipLaunchKernelGGL(k_fid, dim3(1024), dim3(256), 0, stream, QH, QL, KH, KL, attn);
  hipLaunchKernelGGL(k_pv, dim3(1024), dim3(256), 0, stream, attn, VTH, VTL, ctx);
}

// Round 6
// 237.022 us; speedup vs baseline: 1.2800x; 1.2800x over previous
//
#include <hip/hip_runtime.h>
#include <math.h>

#define PI_F 3.14159265358979323846f

constexpr int Bq = 8, Lq = 1024, Sq = 1024, Hq = 8, Dq = 64;

typedef short short8 __attribute__((ext_vector_type(8)));
typedef float f4v __attribute__((ext_vector_type(4)));
typedef unsigned short ushort_t;

static __device__ __forceinline__ ushort_t f2bf(float x) {
  union { float f; unsigned u; } v; v.f = x;
  unsigned r = v.u + 0x7fffu + ((v.u >> 16) & 1u);   // RNE
  return (ushort_t)(r >> 16);
}
static __device__ __forceinline__ float bf2f(ushort_t b) {
  union { unsigned u; float f; } v; v.u = ((unsigned)b) << 16;
  return v.f;
}
static __device__ __forceinline__ f4v mfma16(short8 a, short8 b, f4v c) {
  return __builtin_amdgcn_mfma_f32_16x16x32_bf16(a, b, c, 0, 0, 0);
}
// q~' from q~: pairs (re,im) -> (im,-re); bf16 negate = sign-bit flip
static __device__ __forceinline__ short8 primef(short8 q) {
  short8 r;
#pragma unroll
  for (int i = 0; i < 4; ++i) {
    r[2 * i]     = q[2 * i + 1];
    r[2 * i + 1] = (short)(((ushort_t)q[2 * i]) ^ 0x8000u);
  }
  return r;
}

// ---------------------------------------------------------------------------
// state-math: angles -> diag -> WHT -> st[32] interleaved (re,im) f32
// ---------------------------------------------------------------------------
static __device__ __forceinline__ void state_vec(
    const float* __restrict__ x, const float lw[4][64], const float lb[4],
    int n, float st[32])
{
  const float4* xp = (const float4*)(x + (size_t)n * 64);
  float a0 = lb[0], a1 = lb[1], a2 = lb[2], a3 = lb[3];
#pragma unroll
  for (int i = 0; i < 16; ++i) {
    float4 v = xp[i];
    a0 += v.x * lw[0][4*i] + v.y * lw[0][4*i+1] + v.z * lw[0][4*i+2] + v.w * lw[0][4*i+3];
    a1 += v.x * lw[1][4*i] + v.y * lw[1][4*i+1] + v.z * lw[1][4*i+2] + v.w * lw[1][4*i+3];
    a2 += v.x * lw[2][4*i] + v.y * lw[2][4*i+1] + v.z * lw[2][4*i+2] + v.w * lw[2][4*i+3];
    a3 += v.x * lw[3][4*i] + v.y * lw[3][4*i+1] + v.z * lw[3][4*i+2] + v.w * lw[3][4*i+3];
  }
  a0 = tanhf(a0) * PI_F; a1 = tanhf(a1) * PI_F;
  a2 = tanhf(a2) * PI_F; a3 = tanhf(a3) * PI_F;
  float p01 = a0 * a1, p12 = a1 * a2, p23 = a2 * a3;

  float dr[16], di[16];
#pragma unroll
  for (int d = 0; d < 16; ++d) {
    float s0 = (d & 8) ? -1.f : 1.f;
    float s1 = (d & 4) ? -1.f : 1.f;
    float s2 = (d & 2) ? -1.f : 1.f;
    float s3 = (d & 1) ? -1.f : 1.f;
    float arg = a0*s0 + a1*s1 + a2*s2 + a3*s3
              + p01*s0*s1 + p12*s1*s2 + p23*s2*s3;
    float sn, cs;
    sincosf(0.5f * arg, &sn, &cs);
    dr[d] = cs; di[d] = -sn;
  }
  float hr[16], hi[16];
#pragma unroll
  for (int i = 0; i < 16; ++i) { hr[i] = dr[i]; hi[i] = di[i]; }
#pragma unroll
  for (int stp = 1; stp < 16; stp <<= 1) {
#pragma unroll
    for (int i = 0; i < 16; ++i) {
      if (!(i & stp)) {
        float xr = hr[i], yr = hr[i + stp];
        hr[i] = xr + yr; hr[i + stp] = xr - yr;
        float xi = hi[i], yi = hi[i + stp];
        hi[i] = xi + yi; hi[i + stp] = xi - yi;
      }
    }
  }
#pragma unroll
  for (int d = 0; d < 16; ++d) {
    st[2*d]   = (dr[d] * hr[d] - di[d] * hi[d]) * 0.0625f;
    st[2*d+1] = (dr[d] * hi[d] + di[d] * hr[d]) * 0.0625f;
  }
}

static __device__ __forceinline__ void pack_store(
    const float st[32], ushort_t* __restrict__ outH,
    ushort_t* __restrict__ outL, size_t rb)
{
  unsigned uh[16], ul[16];
#pragma unroll
  for (int d = 0; d < 16; ++d) {
    ushort_t rh = f2bf(st[2*d]), ih = f2bf(st[2*d+1]);
    ushort_t rl = f2bf(st[2*d]   - bf2f(rh));
    ushort_t il = f2bf(st[2*d+1] - bf2f(ih));
    uh[d] = (unsigned)rh | ((unsigned)ih << 16);
    ul[d] = (unsigned)rl | ((unsigned)il << 16);
  }
  uint4* ph = (uint4*)(outH + rb);
  uint4* pl = (uint4*)(outL + rb);
#pragma unroll
  for (int i = 0; i < 4; ++i) {
    ph[i] = make_uint4(uh[4*i], uh[4*i+1], uh[4*i+2], uh[4*i+3]);
    pl[i] = make_uint4(ul[4*i], ul[4*i+1], ul[4*i+2], ul[4*i+3]);
  }
}

// ---------------------------------------------------------------------------
// k_states2: states as bf16 hi/lo.  [(b*8+h)*1024 + l][32].
// ---------------------------------------------------------------------------
__global__ __launch_bounds__(256) void k_states2(
    const float* __restrict__ x, const float* __restrict__ w,
    const float* __restrict__ bias, ushort_t* __restrict__ outH,
    ushort_t* __restrict__ outL)
{
  __shared__ float lw[4][64];
  __shared__ float lb[4];
  int t = threadIdx.x;
  lw[t >> 6][t & 63] = w[t];
  if (t < 4) lb[t] = bias[t];
  __syncthreads();

  int n = blockIdx.x * 256 + t;
  float st[32];
  state_vec(x, lw, lb, n, st);
  int b = n >> 13, l = (n >> 3) & 1023, h = n & 7;
  pack_store(st, outH, outL, ((size_t)(b * Hq + h) * Lq + l) * 32);
}

// ---------------------------------------------------------------------------
// k_vt: V [B][S][H][64] f32 -> VT [bh][d][s] bf16 (hi only; V-lo term is
// below the context error budget).
// ---------------------------------------------------------------------------
__global__ __launch_bounds__(256) void k_vt(
    const float* __restrict__ v, ushort_t* __restrict__ vtH)
{
  __shared__ float tile[64 * 68];
  int bid = blockIdx.x;
  int bh = bid >> 4, s0 = (bid & 15) << 6;
  int b = bh >> 3, h = bh & 7;
  int t = threadIdx.x;
  int sl = t >> 2, dq = (t & 3) << 4;
  const float4* src = (const float4*)(v + (((size_t)b * Sq + s0 + sl) * Hq + h) * 64 + dq);
#pragma unroll
  for (int i = 0; i < 4; ++i)
    *(float4*)&tile[sl * 68 + dq + 4 * i] = src[i];
  __syncthreads();
  int d = t >> 2, sq = (t & 3) << 4;
  unsigned hw[8];
#pragma unroll
  for (int j = 0; j < 8; ++j) {
    float x0 = tile[(sq + 2*j)     * 68 + d];
    float x1 = tile[(sq + 2*j + 1) * 68 + d];
    hw[j] = (unsigned)f2bf(x0) | ((unsigned)f2bf(x1) << 16);
  }
  size_t ob = ((size_t)bh * 64 + d) * 1024 + s0 + sq;
  uint4* oh = (uint4*)(vtH + ob);
  oh[0] = make_uint4(hw[0], hw[1], hw[2], hw[3]);
  oh[1] = make_uint4(hw[4], hw[5], hw[6], hw[7]);
}

// ---------------------------------------------------------------------------
// k_fid: normalized attention scores, nothing else.
// 1024 blocks (bh, 64-row tile), 4 waves x 16 rows, full 1024 s per wave.
// ---------------------------------------------------------------------------
__global__ __launch_bounds__(256) void k_fid(
    const ushort_t* __restrict__ QH, const ushort_t* __restrict__ QL,
    const ushort_t* __restrict__ KH, const ushort_t* __restrict__ KL,
    float* __restrict__ attn)
{
  __shared__ float Wtr[4][16 * 68];

  int bid = blockIdx.x;                 // 1024 (%8==0 -> bijective swizzle)
  int xcd = bid & 7, idx = bid >> 3;
  int bh = (xcd << 3) | (idx >> 4);
  int l0 = (idx & 15) << 6;
  int t = threadIdx.x;
  int wv = t >> 6, lane = t & 63;
  int lh = lane & 15, g = lane >> 4, ko = g << 3;
  int rowbase = l0 + (wv << 4);

  size_t qoff = ((size_t)bh * Lq + rowbase + lh) * 32 + ko;
  short8 qh  = *(const short8*)(QH + qoff);
  short8 ql  = *(const short8*)(QL + qoff);
  short8 qph = primef(qh), qpl = primef(ql);

  const ushort_t* kbh = KH + ((size_t)bh * Sq + lh) * 32 + ko;
  const ushort_t* kbl = KL + ((size_t)bh * Sq + lh) * 32 + ko;

  f4v zero = {0.f, 0.f, 0.f, 0.f};

  // ---- pass 1: rowsum, hi-only fid ----
  float rsum = 0.f;
  for (int sf = 0; sf < 64; ++sf) {
    short8 kh = *(const short8*)(kbh + sf * 512);
    f4v fr = mfma16(kh, qh, zero);
    f4v fi = mfma16(kh, qph, zero);
#pragma unroll
    for (int r = 0; r < 4; ++r) rsum += fr[r]*fr[r] + fi[r]*fi[r];
  }
  rsum += __shfl_xor(rsum, 16);
  rsum += __shfl_xor(rsum, 32);
  float rinv = 1.f / (rsum + 1e-6f);

  // ---- pass 2: split-3 fid -> normalize -> transpose -> store ----
  float* abase = attn + ((size_t)bh * Lq + rowbase) * Sq;
  float* wtr = &Wtr[wv][0];

  for (int c = 0; c < 16; ++c) {
    int coff = c * 2048;                // (c*64)*32
#pragma unroll
    for (int f = 0; f < 4; ++f) {
      short8 kh = *(const short8*)(kbh + coff + f * 512);
      short8 kl = *(const short8*)(kbl + coff + f * 512);
      f4v fr = mfma16(kh, qh, zero);
      fr = mfma16(kl, qh, fr);
      fr = mfma16(kh, ql, fr);
      f4v fi = mfma16(kh, qph, zero);
      fi = mfma16(kl, qph, fi);
      fi = mfma16(kh, qpl, fi);
      f4v wv4;
#pragma unroll
      for (int r = 0; r < 4; ++r)
        wv4[r] = (fr[r]*fr[r] + fi[r]*fi[r]) * rinv;
      *(f4v*)&wtr[lh * 68 + (f << 4) + (g << 2)] = wv4;
    }
    // per-wave transpose readback -> coalesced stores (4 rows x 256 B each)
#pragma unroll
    for (int j = 0; j < 4; ++j) {
      int rowp = (j << 2) + g;
      f4v vv = *(const f4v*)&wtr[rowp * 68 + (lh << 2)];
      *(f4v*)(abase + (size_t)rowp * Sq + (c << 6) + (lh << 2)) = vv;
    }
  }
}

// ---------------------------------------------------------------------------
// k_pv2: ctx = attn . V   (per bh: [1024 x 1024] x [1024 x 64], K=1024)
// 1024 blocks (bh, 64-row tile), 4 waves x 16 rows.
// Depth-3 NAMED register pipeline for A (f32 attn rows) and B (VT bf16 hi);
// fully unrolled so all buffer indices are compile-time (no scratch).
// W split hi/lo inline (2 MFMA per d-block); V is hi-only.
// ---------------------------------------------------------------------------
__global__ __launch_bounds__(256, 4) void k_pv2(
    const float* __restrict__ attn, const ushort_t* __restrict__ VTH,
    float* __restrict__ ctx)
{
  int bid = blockIdx.x;                 // 1024
  int xcd = bid & 7, idx = bid >> 3;
  int bh = (xcd << 3) | (idx >> 4);     // all 16 l-tiles of a bh on one XCD
  int l0 = (idx & 15) << 6;
  int t = threadIdx.x;
  int wv = t >> 6, lane = t & 63;
  int lh = lane & 15, g = lane >> 4;
  int rowbase = l0 + (wv << 4);

  const float* arow = attn + ((size_t)bh * Lq + rowbase + lh) * Sq + (g << 3);
  const ushort_t* vh0 = VTH + ((size_t)bh * 64 + lh) * Sq + (g << 3);

  f4v zero = {0.f, 0.f, 0.f, 0.f};
  f4v acc[4] = {zero, zero, zero, zero};

  float4 aB[3][2];
  short8 vB[3][4];

  // prologue: issue iters 0 and 1
#pragma unroll
  for (int p = 0; p < 2; ++p) {
    aB[p][0] = *(const float4*)(arow + p * 32);
    aB[p][1] = *(const float4*)(arow + p * 32 + 4);
#pragma unroll
    for (int f2 = 0; f2 < 4; ++f2)
      vB[p][f2] = *(const short8*)(vh0 + (size_t)(f2 << 4) * Sq + p * 32);
  }

#pragma unroll
  for (int it = 0; it < 32; ++it) {
    const int cur = it % 3, nx = (it + 2) % 3;   // compile-time (unrolled)
    if (it < 30) {
      int s0 = (it + 2) * 32;
      aB[nx][0] = *(const float4*)(arow + s0);
      aB[nx][1] = *(const float4*)(arow + s0 + 4);
#pragma unroll
      for (int f2 = 0; f2 < 4; ++f2)
        vB[nx][f2] = *(const short8*)(vh0 + (size_t)(f2 << 4) * Sq + s0);
    }
    float av[8] = {aB[cur][0].x, aB[cur][0].y, aB[cur][0].z, aB[cur][0].w,
                   aB[cur][1].x, aB[cur][1].y, aB[cur][1].z, aB[cur][1].w};
    short8 wh, wl;
#pragma unroll
    for (int e = 0; e < 8; ++e) {
      union { float f; unsigned u; } cv; cv.f = av[e];
      unsigned tu = cv.u & 0xFFFF0000u;
      union { unsigned u; float f; } hv; hv.u = tu;
      wh[e] = (short)(tu >> 16);
      wl[e] = (short)f2bf(av[e] - hv.f);
    }
#pragma unroll
    for (int f2 = 0; f2 < 4; ++f2) {
      acc[f2] = mfma16(wh, vB[cur][f2], acc[f2]);
      acc[f2] = mfma16(wl, vB[cur][f2], acc[f2]);
    }
  }

  int b = bh >> 3, h = bh & 7;
#pragma unroll
  for (int f2 = 0; f2 < 4; ++f2) {
    int d = (f2 << 4) + lh;
#pragma unroll
    for (int r = 0; r < 4; ++r) {
      int l = rowbase + (g << 2) + r;
      ctx[(((size_t)b * Lq + l) * Hq + h) * 64 + d] = acc[f2][r];
    }
  }
}

// ===========================================================================
extern "C" void kernel_launch(void* const* d_in, const int* in_sizes, int n_in,
                              void* d_out, int out_size, void* d_ws, size_t ws_size,
                              hipStream_t stream) {
  const float* q  = (const float*)d_in[0];
  const float* k  = (const float*)d_in[1];
  const float* v  = (const float*)d_in[2];
  const float* wq = (const float*)d_in[3];
  const float* bq = (const float*)d_in[4];
  const float* wk = (const float*)d_in[5];
  const float* bk = (const float*)d_in[6];

  float* out  = (float*)d_out;
  float* ctx  = out;                    // [B,L,H,D]  = 4,194,304 floats
  float* attn = out + 4194304;          // [B,H,L,S]  = 67,108,864 floats

  char* wsb = (char*)d_ws;
  ushort_t* QH  = (ushort_t*)(wsb);
  ushort_t* QL  = (ushort_t*)(wsb + (size_t)4  * 1024 * 1024);
  ushort_t* KH  = (ushort_t*)(wsb + (size_t)8  * 1024 * 1024);
  ushort_t* KL  = (ushort_t*)(wsb + (size_t)12 * 1024 * 1024);
  ushort_t* VTH = (ushort_t*)(wsb + (size_t)16 * 1024 * 1024);

  hipLaunchKernelGGL(k_states2, dim3(256), dim3(256), 0, stream, q, wq, bq, QH, QL);
  hipLaunchKernelGGL(k_states2, dim3(256), dim3(256), 0, stream, k, wk, bk, KH, KL);
  hipLaunchKernelGGL(k_vt, dim3(1024), dim3(256), 0, stream, v, VTH);
  hipLaunchKernelGGL(k_fid, dim3(1024), dim3(256), 0, stream, QH, QL, KH, KL, attn);
  hipLaunchKernelGGL(k_pv2, dim3(1024), dim3(256), 0, stream, attn, VTH, ctx);
}

// Round 7
// 230.105 us; speedup vs baseline: 1.3185x; 1.0301x over previous
//
#include <hip/hip_runtime.h>
#include <math.h>

#define PI_F 3.14159265358979323846f

constexpr int Bq = 8, Lq = 1024, Sq = 1024, Hq = 8, Dq = 64;

typedef short short8 __attribute__((ext_vector_type(8)));
typedef float f4v __attribute__((ext_vector_type(4)));
typedef unsigned short ushort_t;

static __device__ __forceinline__ ushort_t f2bf(float x) {
  union { float f; unsigned u; } v; v.f = x;
  unsigned r = v.u + 0x7fffu + ((v.u >> 16) & 1u);   // RNE
  return (ushort_t)(r >> 16);
}
static __device__ __forceinline__ float bf2f(ushort_t b) {
  union { unsigned u; float f; } v; v.u = ((unsigned)b) << 16;
  return v.f;
}
static __device__ __forceinline__ f4v mfma16(short8 a, short8 b, f4v c) {
  return __builtin_amdgcn_mfma_f32_16x16x32_bf16(a, b, c, 0, 0, 0);
}
// q~' from q~: pairs (re,im) -> (im,-re); bf16 negate = sign-bit flip
static __device__ __forceinline__ short8 primef(short8 q) {
  short8 r;
#pragma unroll
  for (int i = 0; i < 4; ++i) {
    r[2 * i]     = q[2 * i + 1];
    r[2 * i + 1] = (short)(((ushort_t)q[2 * i]) ^ 0x8000u);
  }
  return r;
}
// async 16B global -> LDS (per-lane global addr, wave-uniform LDS base)
static __device__ __forceinline__ void gl_lds16(const void* g, void* l) {
  __builtin_amdgcn_global_load_lds(
      (const __attribute__((address_space(1))) unsigned int*)g,
      (__attribute__((address_space(3))) unsigned int*)l, 16, 0, 0);
}

// ---------------------------------------------------------------------------
// state-math: angles -> diag -> WHT -> st[32] interleaved (re,im) f32
// ---------------------------------------------------------------------------
static __device__ __forceinline__ void state_vec(
    const float* __restrict__ x, const float lw[4][64], const float lb[4],
    int n, float st[32])
{
  const float4* xp = (const float4*)(x + (size_t)n * 64);
  float a0 = lb[0], a1 = lb[1], a2 = lb[2], a3 = lb[3];
#pragma unroll
  for (int i = 0; i < 16; ++i) {
    float4 v = xp[i];
    a0 += v.x * lw[0][4*i] + v.y * lw[0][4*i+1] + v.z * lw[0][4*i+2] + v.w * lw[0][4*i+3];
    a1 += v.x * lw[1][4*i] + v.y * lw[1][4*i+1] + v.z * lw[1][4*i+2] + v.w * lw[1][4*i+3];
    a2 += v.x * lw[2][4*i] + v.y * lw[2][4*i+1] + v.z * lw[2][4*i+2] + v.w * lw[2][4*i+3];
    a3 += v.x * lw[3][4*i] + v.y * lw[3][4*i+1] + v.z * lw[3][4*i+2] + v.w * lw[3][4*i+3];
  }
  a0 = tanhf(a0) * PI_F; a1 = tanhf(a1) * PI_F;
  a2 = tanhf(a2) * PI_F; a3 = tanhf(a3) * PI_F;
  float p01 = a0 * a1, p12 = a1 * a2, p23 = a2 * a3;

  float dr[16], di[16];
#pragma unroll
  for (int d = 0; d < 16; ++d) {
    float s0 = (d & 8) ? -1.f : 1.f;
    float s1 = (d & 4) ? -1.f : 1.f;
    float s2 = (d & 2) ? -1.f : 1.f;
    float s3 = (d & 1) ? -1.f : 1.f;
    float arg = a0*s0 + a1*s1 + a2*s2 + a3*s3
              + p01*s0*s1 + p12*s1*s2 + p23*s2*s3;
    float sn, cs;
    sincosf(0.5f * arg, &sn, &cs);
    dr[d] = cs; di[d] = -sn;
  }
  float hr[16], hi[16];
#pragma unroll
  for (int i = 0; i < 16; ++i) { hr[i] = dr[i]; hi[i] = di[i]; }
#pragma unroll
  for (int stp = 1; stp < 16; stp <<= 1) {
#pragma unroll
    for (int i = 0; i < 16; ++i) {
      if (!(i & stp)) {
        float xr = hr[i], yr = hr[i + stp];
        hr[i] = xr + yr; hr[i + stp] = xr - yr;
        float xi = hi[i], yi = hi[i + stp];
        hi[i] = xi + yi; hi[i + stp] = xi - yi;
      }
    }
  }
#pragma unroll
  for (int d = 0; d < 16; ++d) {
    st[2*d]   = (dr[d] * hr[d] - di[d] * hi[d]) * 0.0625f;
    st[2*d+1] = (dr[d] * hi[d] + di[d] * hr[d]) * 0.0625f;
  }
}

static __device__ __forceinline__ void pack_store(
    const float st[32], ushort_t* __restrict__ outH,
    ushort_t* __restrict__ outL, size_t rb)
{
  unsigned uh[16], ul[16];
#pragma unroll
  for (int d = 0; d < 16; ++d) {
    ushort_t rh = f2bf(st[2*d]), ih = f2bf(st[2*d+1]);
    ushort_t rl = f2bf(st[2*d]   - bf2f(rh));
    ushort_t il = f2bf(st[2*d+1] - bf2f(ih));
    uh[d] = (unsigned)rh | ((unsigned)ih << 16);
    ul[d] = (unsigned)rl | ((unsigned)il << 16);
  }
  uint4* ph = (uint4*)(outH + rb);
  uint4* pl = (uint4*)(outL + rb);
#pragma unroll
  for (int i = 0; i < 4; ++i) {
    ph[i] = make_uint4(uh[4*i], uh[4*i+1], uh[4*i+2], uh[4*i+3]);
    pl[i] = make_uint4(ul[4*i], ul[4*i+1], ul[4*i+2], ul[4*i+3]);
  }
}

// ---------------------------------------------------------------------------
// k_states2: states as bf16 hi/lo.  [(b*8+h)*1024 + l][32].
// ---------------------------------------------------------------------------
__global__ __launch_bounds__(256) void k_states2(
    const float* __restrict__ x, const float* __restrict__ w,
    const float* __restrict__ bias, ushort_t* __restrict__ outH,
    ushort_t* __restrict__ outL)
{
  __shared__ float lw[4][64];
  __shared__ float lb[4];
  int t = threadIdx.x;
  lw[t >> 6][t & 63] = w[t];
  if (t < 4) lb[t] = bias[t];
  __syncthreads();

  int n = blockIdx.x * 256 + t;
  float st[32];
  state_vec(x, lw, lb, n, st);
  int b = n >> 13, l = (n >> 3) & 1023, h = n & 7;
  pack_store(st, outH, outL, ((size_t)(b * Hq + h) * Lq + l) * 32);
}

// ---------------------------------------------------------------------------
// k_vt: V [B][S][H][64] f32 -> VT [bh][d][s] bf16 (hi only)
// ---------------------------------------------------------------------------
__global__ __launch_bounds__(256) void k_vt(
    const float* __restrict__ v, ushort_t* __restrict__ vtH)
{
  __shared__ float tile[64 * 68];
  int bid = blockIdx.x;
  int bh = bid >> 4, s0 = (bid & 15) << 6;
  int b = bh >> 3, h = bh & 7;
  int t = threadIdx.x;
  int sl = t >> 2, dq = (t & 3) << 4;
  const float4* src = (const float4*)(v + (((size_t)b * Sq + s0 + sl) * Hq + h) * 64 + dq);
#pragma unroll
  for (int i = 0; i < 4; ++i)
    *(float4*)&tile[sl * 68 + dq + 4 * i] = src[i];
  __syncthreads();
  int d = t >> 2, sq = (t & 3) << 4;
  unsigned hw[8];
#pragma unroll
  for (int j = 0; j < 8; ++j) {
    float x0 = tile[(sq + 2*j)     * 68 + d];
    float x1 = tile[(sq + 2*j + 1) * 68 + d];
    hw[j] = (unsigned)f2bf(x0) | ((unsigned)f2bf(x1) << 16);
  }
  size_t ob = ((size_t)bh * 64 + d) * 1024 + s0 + sq;
  uint4* oh = (uint4*)(vtH + ob);
  oh[0] = make_uint4(hw[0], hw[1], hw[2], hw[3]);
  oh[1] = make_uint4(hw[4], hw[5], hw[6], hw[7]);
}

// ---------------------------------------------------------------------------
// k_fid: normalized attention scores.
// 1024 blocks (bh, 64-row tile), 4 waves x 16 rows, full 1024 s per wave.
// ---------------------------------------------------------------------------
__global__ __launch_bounds__(256) void k_fid(
    const ushort_t* __restrict__ QH, const ushort_t* __restrict__ QL,
    const ushort_t* __restrict__ KH, const ushort_t* __restrict__ KL,
    float* __restrict__ attn)
{
  __shared__ float Wtr[4][16 * 68];

  int bid = blockIdx.x;                 // 1024 (%8==0 -> bijective swizzle)
  int xcd = bid & 7, idx = bid >> 3;
  int bh = (xcd << 3) | (idx >> 4);
  int l0 = (idx & 15) << 6;
  int t = threadIdx.x;
  int wv = t >> 6, lane = t & 63;
  int lh = lane & 15, g = lane >> 4, ko = g << 3;
  int rowbase = l0 + (wv << 4);

  size_t qoff = ((size_t)bh * Lq + rowbase + lh) * 32 + ko;
  short8 qh  = *(const short8*)(QH + qoff);
  short8 ql  = *(const short8*)(QL + qoff);
  short8 qph = primef(qh), qpl = primef(ql);

  const ushort_t* kbh = KH + ((size_t)bh * Sq + lh) * 32 + ko;
  const ushort_t* kbl = KL + ((size_t)bh * Sq + lh) * 32 + ko;

  f4v zero = {0.f, 0.f, 0.f, 0.f};

  // ---- pass 1: rowsum, hi-only fid ----
  float rsum = 0.f;
  for (int sf = 0; sf < 64; ++sf) {
    short8 kh = *(const short8*)(kbh + sf * 512);
    f4v fr = mfma16(kh, qh, zero);
    f4v fi = mfma16(kh, qph, zero);
#pragma unroll
    for (int r = 0; r < 4; ++r) rsum += fr[r]*fr[r] + fi[r]*fi[r];
  }
  rsum += __shfl_xor(rsum, 16);
  rsum += __shfl_xor(rsum, 32);
  float rinv = 1.f / (rsum + 1e-6f);

  // ---- pass 2: split-3 fid -> normalize -> transpose -> store ----
  float* abase = attn + ((size_t)bh * Lq + rowbase) * Sq;
  float* wtr = &Wtr[wv][0];

  for (int c = 0; c < 16; ++c) {
    int coff = c * 2048;                // (c*64)*32
#pragma unroll
    for (int f = 0; f < 4; ++f) {
      short8 kh = *(const short8*)(kbh + coff + f * 512);
      short8 kl = *(const short8*)(kbl + coff + f * 512);
      f4v fr = mfma16(kh, qh, zero);
      fr = mfma16(kl, qh, fr);
      fr = mfma16(kh, ql, fr);
      f4v fi = mfma16(kh, qph, zero);
      fi = mfma16(kl, qph, fi);
      fi = mfma16(kh, qpl, fi);
      f4v wv4;
#pragma unroll
      for (int r = 0; r < 4; ++r)
        wv4[r] = (fr[r]*fr[r] + fi[r]*fi[r]) * rinv;
      *(f4v*)&wtr[lh * 68 + (f << 4) + (g << 2)] = wv4;
    }
    // per-wave transpose readback -> coalesced stores (4 rows x 256 B each)
#pragma unroll
    for (int j = 0; j < 4; ++j) {
      int rowp = (j << 2) + g;
      f4v vv = *(const f4v*)&wtr[rowp * 68 + (lh << 2)];
      *(f4v*)(abase + (size_t)rowp * Sq + (c << 6) + (lh << 2)) = vv;
    }
  }
}

// ---------------------------------------------------------------------------
// k_pv3: ctx = attn . V, 2-phase global_load_lds-staged GEMM.
// 1024 blocks (bh, 64-row tile), 4 waves x 16 rows; K-step 32.
// Per buffer: A = attn[64 rows][32 s] f32 (8 KB, XOR granule^=(r&7)),
//             B = VT [64 d][32 s] bf16 (4 KB, XOR granule^=(d&3)).
// 24 KB LDS double-buffered; STAGE(next) -> ds_read+MFMA(cur) -> barrier.
// W = bf16-hi only (ctx err ~6e-5 << threshold).
// ---------------------------------------------------------------------------
__global__ __launch_bounds__(256) void k_pv3(
    const float* __restrict__ attn, const ushort_t* __restrict__ VTH,
    float* __restrict__ ctx)
{
  __shared__ char lds[24576];           // 2 x (8 KB A + 4 KB B)

  int bid = blockIdx.x;                 // 1024
  int xcd = bid & 7, idx = bid >> 3;
  int bh = (xcd << 3) | (idx >> 4);     // all 16 l-tiles of a bh on one XCD
  int l0 = (idx & 15) << 6;
  int t = threadIdx.x;
  int wv = t >> 6, lane = t & 63;
  int lh = lane & 15, g = lane >> 4;

  // ---- staging source addresses (pre-swizzled global columns) ----
  // A: rows r = it*32 + wv*8 + (lane>>3), granule c16 = lane&7, col float
  //    = ((c16 ^ (r&7)) << 2);  r&7 == (lane>>3)&7  (wv*8, it*32 = 0 mod 8)
  int rA = (wv << 3) + (lane >> 3);
  int colA = (((lane & 7) ^ ((lane >> 3) & 7)) << 2);
  const float* gA0 = attn + (size_t)bh * Lq * Sq + (size_t)(l0 + rA) * Sq + colA;
  const float* gA1 = gA0 + (size_t)32 * Sq;
  // B: d = wv*16 + (lane>>2), granule c16 = lane&3, col bf16
  //    = ((c16 ^ (d&3)) << 3);  d&3 == (lane>>2)&3
  int dB = (wv << 4) + (lane >> 2);
  int colB = (((lane & 3) ^ ((lane >> 2) & 3)) << 3);
  const ushort_t* gB0 = VTH + ((size_t)bh * 64 + dB) * Sq + colB;

  // wave-uniform LDS staging bases
  char* ldsA0 = lds + (wv << 10);
  char* ldsA1 = lds + 4096 + (wv << 10);
  char* ldsB0 = lds + 8192 + (wv << 10);

  // ---- ds_read addresses (same XOR as source pre-swizzle) ----
  // A: r = wv*16+lh, granule (g*2+e) ^ (lh&7)
  int rdA = ((wv << 4) + lh) << 7;      // r*128
  int pa0 = rdA + ((((g << 1) | 0) ^ (lh & 7)) << 4);
  int pa1 = rdA + ((((g << 1) | 1) ^ (lh & 7)) << 4);
  // B: d = f2*16+lh, granule g ^ (lh&3); byte = 8192 + d*64 + phys*16
  int pb = 8192 + (lh << 6) + ((g ^ (lh & 3)) << 4);

  f4v zero = {0.f, 0.f, 0.f, 0.f};
  f4v acc[4] = {zero, zero, zero, zero};

#define PV_STAGE(p, step) do {                                   \
    int so_ = (step) << 5;                                       \
    gl_lds16(gA0 + so_, ldsA0 + (p) * 12288);                    \
    gl_lds16(gA1 + so_, ldsA1 + (p) * 12288);                    \
    gl_lds16(gB0 + so_, ldsB0 + (p) * 12288);                    \
  } while (0)

  PV_STAGE(0, 0);
  __syncthreads();

#pragma unroll
  for (int tt = 0; tt < 32; ++tt) {
    const int cur = tt & 1;
    if (tt < 31) PV_STAGE(cur ^ 1, tt + 1);
    const char* base = lds + cur * 12288;
    f4v a0 = *(const f4v*)(base + pa0);
    f4v a1 = *(const f4v*)(base + pa1);
    short8 wh;
#pragma unroll
    for (int e = 0; e < 4; ++e) wh[e] = (short)f2bf(a0[e]);
#pragma unroll
    for (int e = 0; e < 4; ++e) wh[4 + e] = (short)f2bf(a1[e]);
#pragma unroll
    for (int f2 = 0; f2 < 4; ++f2) {
      short8 vb = *(const short8*)(base + pb + (f2 << 10));  // d += 16 -> +1024B
      acc[f2] = mfma16(wh, vb, acc[f2]);
    }
    __syncthreads();
  }
#undef PV_STAGE

  int b = bh >> 3, h = bh & 7;
#pragma unroll
  for (int f2 = 0; f2 < 4; ++f2) {
    int d = (f2 << 4) + lh;
#pragma unroll
    for (int r = 0; r < 4; ++r) {
      int l = l0 + (wv << 4) + (g << 2) + r;
      ctx[(((size_t)b * Lq + l) * Hq + h) * 64 + d] = acc[f2][r];
    }
  }
}

// ===========================================================================
extern "C" void kernel_launch(void* const* d_in, const int* in_sizes, int n_in,
                              void* d_out, int out_size, void* d_ws, size_t ws_size,
                              hipStream_t stream) {
  const float* q  = (const float*)d_in[0];
  const float* k  = (const float*)d_in[1];
  const float* v  = (const float*)d_in[2];
  const float* wq = (const float*)d_in[3];
  const float* bq = (const float*)d_in[4];
  const float* wk = (const float*)d_in[5];
  const float* bk = (const float*)d_in[6];

  float* out  = (float*)d_out;
  float* ctx  = out;                    // [B,L,H,D]  = 4,194,304 floats
  float* attn = out + 4194304;          // [B,H,L,S]  = 67,108,864 floats

  char* wsb = (char*)d_ws;
  ushort_t* QH  = (ushort_t*)(wsb);
  ushort_t* QL  = (ushort_t*)(wsb + (size_t)4  * 1024 * 1024);
  ushort_t* KH  = (ushort_t*)(wsb + (size_t)8  * 1024 * 1024);
  ushort_t* KL  = (ushort_t*)(wsb + (size_t)12 * 1024 * 1024);
  ushort_t* VTH = (ushort_t*)(wsb + (size_t)16 * 1024 * 1024);

  hipLaunchKernelGGL(k_states2, dim3(256), dim3(256), 0, stream, q, wq, bq, QH, QL);
  hipLaunchKernelGGL(k_states2, dim3(256), dim3(256), 0, stream, k, wk, bk, KH, KL);
  hipLaunchKernelGGL(k_vt, dim3(1024), dim3(256), 0, stream, v, VTH);
  hipLaunchKernelGGL(k_fid, dim3(1024), dim3(256), 0, stream, QH, QL, KH, KL, attn);
  hipLaunchKernelGGL(k_pv3, dim3(1024), dim3(256), 0, stream, attn, VTH, ctx);
}

// Round 8
// 199.005 us; speedup vs baseline: 1.5245x; 1.1563x over previous
//
#include <hip/hip_runtime.h>
#include <math.h>

#define PI_F 3.14159265358979323846f

constexpr int Bq = 8, Lq = 1024, Sq = 1024, Hq = 8, Dq = 64;

typedef short short8 __attribute__((ext_vector_type(8)));
typedef float f4v __attribute__((ext_vector_type(4)));
typedef unsigned short ushort_t;

static __device__ __forceinline__ ushort_t f2bf(float x) {
  union { float f; unsigned u; } v; v.f = x;
  unsigned r = v.u + 0x7fffu + ((v.u >> 16) & 1u);   // RNE
  return (ushort_t)(r >> 16);
}
static __device__ __forceinline__ float bf2f(ushort_t b) {
  union { unsigned u; float f; } v; v.u = ((unsigned)b) << 16;
  return v.f;
}
static __device__ __forceinline__ f4v mfma16(short8 a, short8 b, f4v c) {
  return __builtin_amdgcn_mfma_f32_16x16x32_bf16(a, b, c, 0, 0, 0);
}
// q~' from q~: pairs (re,im) -> (im,-re); bf16 negate = sign-bit flip
static __device__ __forceinline__ short8 primef(short8 q) {
  short8 r;
#pragma unroll
  for (int i = 0; i < 4; ++i) {
    r[2 * i]     = q[2 * i + 1];
    r[2 * i + 1] = (short)(((ushort_t)q[2 * i]) ^ 0x8000u);
  }
  return r;
}
// async 16B global -> LDS (per-lane global addr, wave-uniform LDS base)
static __device__ __forceinline__ void gl_lds16(const void* g, void* l) {
  __builtin_amdgcn_global_load_lds(
      (const __attribute__((address_space(1))) unsigned int*)g,
      (__attribute__((address_space(3))) unsigned int*)l, 16, 0, 0);
}

// ---------------------------------------------------------------------------
// state-math: angles -> diag -> WHT -> st[32] interleaved (re,im) f32
// ---------------------------------------------------------------------------
static __device__ __forceinline__ void state_vec(
    const float* __restrict__ x, const float lw[4][64], const float lb[4],
    int n, float st[32])
{
  const float4* xp = (const float4*)(x + (size_t)n * 64);
  float a0 = lb[0], a1 = lb[1], a2 = lb[2], a3 = lb[3];
#pragma unroll
  for (int i = 0; i < 16; ++i) {
    float4 v = xp[i];
    a0 += v.x * lw[0][4*i] + v.y * lw[0][4*i+1] + v.z * lw[0][4*i+2] + v.w * lw[0][4*i+3];
    a1 += v.x * lw[1][4*i] + v.y * lw[1][4*i+1] + v.z * lw[1][4*i+2] + v.w * lw[1][4*i+3];
    a2 += v.x * lw[2][4*i] + v.y * lw[2][4*i+1] + v.z * lw[2][4*i+2] + v.w * lw[2][4*i+3];
    a3 += v.x * lw[3][4*i] + v.y * lw[3][4*i+1] + v.z * lw[3][4*i+2] + v.w * lw[3][4*i+3];
  }
  a0 = tanhf(a0) * PI_F; a1 = tanhf(a1) * PI_F;
  a2 = tanhf(a2) * PI_F; a3 = tanhf(a3) * PI_F;
  float p01 = a0 * a1, p12 = a1 * a2, p23 = a2 * a3;

  float dr[16], di[16];
#pragma unroll
  for (int d = 0; d < 16; ++d) {
    float s0 = (d & 8) ? -1.f : 1.f;
    float s1 = (d & 4) ? -1.f : 1.f;
    float s2 = (d & 2) ? -1.f : 1.f;
    float s3 = (d & 1) ? -1.f : 1.f;
    float arg = a0*s0 + a1*s1 + a2*s2 + a3*s3
              + p01*s0*s1 + p12*s1*s2 + p23*s2*s3;
    float sn, cs;
    sincosf(0.5f * arg, &sn, &cs);
    dr[d] = cs; di[d] = -sn;
  }
  float hr[16], hi[16];
#pragma unroll
  for (int i = 0; i < 16; ++i) { hr[i] = dr[i]; hi[i] = di[i]; }
#pragma unroll
  for (int stp = 1; stp < 16; stp <<= 1) {
#pragma unroll
    for (int i = 0; i < 16; ++i) {
      if (!(i & stp)) {
        float xr = hr[i], yr = hr[i + stp];
        hr[i] = xr + yr; hr[i + stp] = xr - yr;
        float xi = hi[i], yi = hi[i + stp];
        hi[i] = xi + yi; hi[i + stp] = xi - yi;
      }
    }
  }
#pragma unroll
  for (int d = 0; d < 16; ++d) {
    st[2*d]   = (dr[d] * hr[d] - di[d] * hi[d]) * 0.0625f;
    st[2*d+1] = (dr[d] * hi[d] + di[d] * hr[d]) * 0.0625f;
  }
}

static __device__ __forceinline__ void pack_store(
    const float st[32], ushort_t* __restrict__ outH,
    ushort_t* __restrict__ outL, size_t rb)
{
  unsigned uh[16], ul[16];
#pragma unroll
  for (int d = 0; d < 16; ++d) {
    ushort_t rh = f2bf(st[2*d]), ih = f2bf(st[2*d+1]);
    ushort_t rl = f2bf(st[2*d]   - bf2f(rh));
    ushort_t il = f2bf(st[2*d+1] - bf2f(ih));
    uh[d] = (unsigned)rh | ((unsigned)ih << 16);
    ul[d] = (unsigned)rl | ((unsigned)il << 16);
  }
  uint4* ph = (uint4*)(outH + rb);
  uint4* pl = (uint4*)(outL + rb);
#pragma unroll
  for (int i = 0; i < 4; ++i) {
    ph[i] = make_uint4(uh[4*i], uh[4*i+1], uh[4*i+2], uh[4*i+3]);
    pl[i] = make_uint4(ul[4*i], ul[4*i+1], ul[4*i+2], ul[4*i+3]);
  }
}

// ---------------------------------------------------------------------------
// k_states2: states as bf16 hi/lo.  [(b*8+h)*1024 + l][32].
// ---------------------------------------------------------------------------
__global__ __launch_bounds__(256) void k_states2(
    const float* __restrict__ x, const float* __restrict__ w,
    const float* __restrict__ bias, ushort_t* __restrict__ outH,
    ushort_t* __restrict__ outL)
{
  __shared__ float lw[4][64];
  __shared__ float lb[4];
  int t = threadIdx.x;
  lw[t >> 6][t & 63] = w[t];
  if (t < 4) lb[t] = bias[t];
  __syncthreads();

  int n = blockIdx.x * 256 + t;
  float st[32];
  state_vec(x, lw, lb, n, st);
  int b = n >> 13, l = (n >> 3) & 1023, h = n & 7;
  pack_store(st, outH, outL, ((size_t)(b * Hq + h) * Lq + l) * 32);
}

// ---------------------------------------------------------------------------
// k_vt: V [B][S][H][64] f32 -> VT [bh][d][s] bf16 (hi only)
// ---------------------------------------------------------------------------
__global__ __launch_bounds__(256) void k_vt(
    const float* __restrict__ v, ushort_t* __restrict__ vtH)
{
  __shared__ float tile[64 * 68];
  int bid = blockIdx.x;
  int bh = bid >> 4, s0 = (bid & 15) << 6;
  int b = bh >> 3, h = bh & 7;
  int t = threadIdx.x;
  int sl = t >> 2, dq = (t & 3) << 4;
  const float4* src = (const float4*)(v + (((size_t)b * Sq + s0 + sl) * Hq + h) * 64 + dq);
#pragma unroll
  for (int i = 0; i < 4; ++i)
    *(float4*)&tile[sl * 68 + dq + 4 * i] = src[i];
  __syncthreads();
  int d = t >> 2, sq = (t & 3) << 4;
  unsigned hw[8];
#pragma unroll
  for (int j = 0; j < 8; ++j) {
    float x0 = tile[(sq + 2*j)     * 68 + d];
    float x1 = tile[(sq + 2*j + 1) * 68 + d];
    hw[j] = (unsigned)f2bf(x0) | ((unsigned)f2bf(x1) << 16);
  }
  size_t ob = ((size_t)bh * 64 + d) * 1024 + s0 + sq;
  uint4* oh = (uint4*)(vtH + ob);
  oh[0] = make_uint4(hw[0], hw[1], hw[2], hw[3]);
  oh[1] = make_uint4(hw[4], hw[5], hw[6], hw[7]);
}

// ---------------------------------------------------------------------------
// k_fid: normalized attention scores.
// 1024 blocks (bh, 64-row tile), 4 waves x 16 rows, full 1024 s per wave.
// ---------------------------------------------------------------------------
__global__ __launch_bounds__(256) void k_fid(
    const ushort_t* __restrict__ QH, const ushort_t* __restrict__ QL,
    const ushort_t* __restrict__ KH, const ushort_t* __restrict__ KL,
    float* __restrict__ attn)
{
  __shared__ float Wtr[4][16 * 68];

  int bid = blockIdx.x;                 // 1024 (%8==0 -> bijective swizzle)
  int xcd = bid & 7, idx = bid >> 3;
  int bh = (xcd << 3) | (idx >> 4);
  int l0 = (idx & 15) << 6;
  int t = threadIdx.x;
  int wv = t >> 6, lane = t & 63;
  int lh = lane & 15, g = lane >> 4, ko = g << 3;
  int rowbase = l0 + (wv << 4);

  size_t qoff = ((size_t)bh * Lq + rowbase + lh) * 32 + ko;
  short8 qh  = *(const short8*)(QH + qoff);
  short8 ql  = *(const short8*)(QL + qoff);
  short8 qph = primef(qh), qpl = primef(ql);

  const ushort_t* kbh = KH + ((size_t)bh * Sq + lh) * 32 + ko;
  const ushort_t* kbl = KL + ((size_t)bh * Sq + lh) * 32 + ko;

  f4v zero = {0.f, 0.f, 0.f, 0.f};

  // ---- pass 1: rowsum, hi-only fid ----
  float rsum = 0.f;
  for (int sf = 0; sf < 64; ++sf) {
    short8 kh = *(const short8*)(kbh + sf * 512);
    f4v fr = mfma16(kh, qh, zero);
    f4v fi = mfma16(kh, qph, zero);
#pragma unroll
    for (int r = 0; r < 4; ++r) rsum += fr[r]*fr[r] + fi[r]*fi[r];
  }
  rsum += __shfl_xor(rsum, 16);
  rsum += __shfl_xor(rsum, 32);
  float rinv = 1.f / (rsum + 1e-6f);

  // ---- pass 2: split-3 fid -> normalize -> transpose -> store ----
  float* abase = attn + ((size_t)bh * Lq + rowbase) * Sq;
  float* wtr = &Wtr[wv][0];

  for (int c = 0; c < 16; ++c) {
    int coff = c * 2048;                // (c*64)*32
#pragma unroll
    for (int f = 0; f < 4; ++f) {
      short8 kh = *(const short8*)(kbh + coff + f * 512);
      short8 kl = *(const short8*)(kbl + coff + f * 512);
      f4v fr = mfma16(kh, qh, zero);
      fr = mfma16(kl, qh, fr);
      fr = mfma16(kh, ql, fr);
      f4v fi = mfma16(kh, qph, zero);
      fi = mfma16(kl, qph, fi);
      fi = mfma16(kh, qpl, fi);
      f4v wv4;
#pragma unroll
      for (int r = 0; r < 4; ++r)
        wv4[r] = (fr[r]*fr[r] + fi[r]*fi[r]) * rinv;
      *(f4v*)&wtr[lh * 68 + (f << 4) + (g << 2)] = wv4;
    }
    // per-wave transpose readback -> coalesced stores (4 rows x 256 B each)
#pragma unroll
    for (int j = 0; j < 4; ++j) {
      int rowp = (j << 2) + g;
      f4v vv = *(const f4v*)&wtr[rowp * 68 + (lh << 2)];
      *(f4v*)(abase + (size_t)rowp * Sq + (c << 6) + (lh << 2)) = vv;
    }
  }
}

// ---------------------------------------------------------------------------
// k_pv4: ctx = attn . V — 3-buffer counted-vmcnt pipeline (T3+T4).
// 1024 blocks (bh, 64-row tile), 4 waves x 16 rows; K-step 32.
// Per buffer (12 KB): A = attn[64r][32s] f32 (8 KB, granule ^= r&7),
//                     B = VT [64d][32s] bf16 (4 KB, granule ^= d&3).
// 3 buffers (36 KB).  Steady state: stage(tt+2) issued each iter; end-of-iter
// s_waitcnt vmcnt(3) keeps stage(tt+2) IN FLIGHT across the raw s_barrier
// (never drain to 0); lgkmcnt(0) before barrier closes read-vs-overwrite.
// W = bf16-hi only (validated: absmax unchanged in rounds 6-7).
// ---------------------------------------------------------------------------
__global__ __launch_bounds__(256) void k_pv4(
    const float* __restrict__ attn, const ushort_t* __restrict__ VTH,
    float* __restrict__ ctx)
{
  __shared__ char lds[36864];           // 3 x (8 KB A + 4 KB B)

  int bid = blockIdx.x;                 // 1024
  int xcd = bid & 7, idx = bid >> 3;
  int bh = (xcd << 3) | (idx >> 4);     // all 16 l-tiles of a bh on one XCD
  int l0 = (idx & 15) << 6;
  int t = threadIdx.x;
  int wv = t >> 6, lane = t & 63;
  int lh = lane & 15, g = lane >> 4;

  // ---- staging source addresses (pre-swizzled global columns) ----
  int rA = (wv << 3) + (lane >> 3);
  int colA = (((lane & 7) ^ ((lane >> 3) & 7)) << 2);
  const float* gA0 = attn + (size_t)bh * Lq * Sq + (size_t)(l0 + rA) * Sq + colA;
  const float* gA1 = gA0 + (size_t)32 * Sq;
  int dB = (wv << 4) + (lane >> 2);
  int colB = (((lane & 3) ^ ((lane >> 2) & 3)) << 3);
  const ushort_t* gB0 = VTH + ((size_t)bh * 64 + dB) * Sq + colB;

  // wave-uniform LDS staging bases (within buffer 0)
  char* ldsA0 = lds + (wv << 10);
  char* ldsA1 = lds + 4096 + (wv << 10);
  char* ldsB0 = lds + 8192 + (wv << 10);

  // ---- ds_read addresses (same XOR as source pre-swizzle) ----
  int rdA = ((wv << 4) + lh) << 7;      // r*128
  int pa0 = rdA + ((((g << 1) | 0) ^ (lh & 7)) << 4);
  int pa1 = rdA + ((((g << 1) | 1) ^ (lh & 7)) << 4);
  int pb = 8192 + (lh << 6) + ((g ^ (lh & 3)) << 4);

  f4v zero = {0.f, 0.f, 0.f, 0.f};
  f4v acc[4] = {zero, zero, zero, zero};

#define PV_STAGE(p, step) do {                                   \
    int so_ = (step) << 5;                                       \
    gl_lds16(gA0 + so_, ldsA0 + (p) * 12288);                    \
    gl_lds16(gA1 + so_, ldsA1 + (p) * 12288);                    \
    gl_lds16(gB0 + so_, ldsB0 + (p) * 12288);                    \
  } while (0)

  // prologue: fill buffers 0 and 1; ensure stage(0) landed everywhere
  PV_STAGE(0, 0);
  PV_STAGE(1, 1);
  asm volatile("s_waitcnt vmcnt(3)" ::: "memory");
  __builtin_amdgcn_s_barrier();

#pragma unroll
  for (int tt = 0; tt < 32; ++tt) {
    __builtin_amdgcn_sched_barrier(0);          // pin reads below barrier
    const int cur = tt % 3;
    if (tt < 30) PV_STAGE((tt + 2) % 3, tt + 2);
    const char* base = lds + cur * 12288;
    f4v a0 = *(const f4v*)(base + pa0);
    f4v a1 = *(const f4v*)(base + pa1);
    short8 wh;
#pragma unroll
    for (int e = 0; e < 4; ++e) wh[e] = (short)f2bf(a0[e]);
#pragma unroll
    for (int e = 0; e < 4; ++e) wh[4 + e] = (short)f2bf(a1[e]);
#pragma unroll
    for (int f2 = 0; f2 < 4; ++f2) {
      short8 vb = *(const short8*)(base + pb + (f2 << 10));
      acc[f2] = mfma16(wh, vb, acc[f2]);
    }
    if (tt < 31) {
      if (tt < 30) asm volatile("s_waitcnt vmcnt(3)" ::: "memory");
      else         asm volatile("s_waitcnt vmcnt(0)" ::: "memory");
      asm volatile("s_waitcnt lgkmcnt(0)" ::: "memory");
      __builtin_amdgcn_s_barrier();
    }
  }
#undef PV_STAGE

  int b = bh >> 3, h = bh & 7;
#pragma unroll
  for (int f2 = 0; f2 < 4; ++f2) {
    int d = (f2 << 4) + lh;
#pragma unroll
    for (int r = 0; r < 4; ++r) {
      int l = l0 + (wv << 4) + (g << 2) + r;
      ctx[(((size_t)b * Lq + l) * Hq + h) * 64 + d] = acc[f2][r];
    }
  }
}

// ===========================================================================
extern "C" void kernel_launch(void* const* d_in, const int* in_sizes, int n_in,
                              void* d_out, int out_size, void* d_ws, size_t ws_size,
                              hipStream_t stream) {
  const float* q  = (const float*)d_in[0];
  const float* k  = (const float*)d_in[1];
  const float* v  = (const float*)d_in[2];
  const float* wq = (const float*)d_in[3];
  const float* bq = (const float*)d_in[4];
  const float* wk = (const float*)d_in[5];
  const float* bk = (const float*)d_in[6];

  float* out  = (float*)d_out;
  float* ctx  = out;                    // [B,L,H,D]  = 4,194,304 floats
  float* attn = out + 4194304;          // [B,H,L,S]  = 67,108,864 floats

  char* wsb = (char*)d_ws;
  ushort_t* QH  = (ushort_t*)(wsb);
  ushort_t* QL  = (ushort_t*)(wsb + (size_t)4  * 1024 * 1024);
  ushort_t* KH  = (ushort_t*)(wsb + (size_t)8  * 1024 * 1024);
  ushort_t* KL  = (ushort_t*)(wsb + (size_t)12 * 1024 * 1024);
  ushort_t* VTH = (ushort_t*)(wsb + (size_t)16 * 1024 * 1024);

  hipLaunchKernelGGL(k_states2, dim3(256), dim3(256), 0, stream, q, wq, bq, QH, QL);
  hipLaunchKernelGGL(k_states2, dim3(256), dim3(256), 0, stream, k, wk, bk, KH, KL);
  hipLaunchKernelGGL(k_vt, dim3(1024), dim3(256), 0, stream, v, VTH);
  hipLaunchKernelGGL(k_fid, dim3(1024), dim3(256), 0, stream, QH, QL, KH, KL, attn);
  hipLaunchKernelGGL(k_pv4, dim3(1024), dim3(256), 0, stream, attn, VTH, ctx);
}

// Round 9
// 169.995 us; speedup vs baseline: 1.7847x; 1.1707x over previous
//
#include <hip/hip_runtime.h>
#include <math.h>

#define PI_F 3.14159265358979323846f

constexpr int Bq = 8, Lq = 1024, Sq = 1024, Hq = 8, Dq = 64;

typedef short short8 __attribute__((ext_vector_type(8)));
typedef float f4v __attribute__((ext_vector_type(4)));
typedef unsigned short ushort_t;

static __device__ __forceinline__ ushort_t f2bf(float x) {
  union { float f; unsigned u; } v; v.f = x;
  unsigned r = v.u + 0x7fffu + ((v.u >> 16) & 1u);   // RNE
  return (ushort_t)(r >> 16);
}
static __device__ __forceinline__ float bf2f(ushort_t b) {
  union { unsigned u; float f; } v; v.u = ((unsigned)b) << 16;
  return v.f;
}
static __device__ __forceinline__ f4v mfma16(short8 a, short8 b, f4v c) {
  return __builtin_amdgcn_mfma_f32_16x16x32_bf16(a, b, c, 0, 0, 0);
}
// q~' from q~: pairs (re,im) -> (im,-re); bf16 negate = sign-bit flip
static __device__ __forceinline__ short8 primef(short8 q) {
  short8 r;
#pragma unroll
  for (int i = 0; i < 4; ++i) {
    r[2 * i]     = q[2 * i + 1];
    r[2 * i + 1] = (short)(((ushort_t)q[2 * i]) ^ 0x8000u);
  }
  return r;
}

// ---------------------------------------------------------------------------
// state-math: angles -> diag -> WHT -> st[32] interleaved (re,im) f32
// ---------------------------------------------------------------------------
static __device__ __forceinline__ void state_vec(
    const float* __restrict__ x, const float lw[4][64], const float lb[4],
    int n, float st[32])
{
  const float4* xp = (const float4*)(x + (size_t)n * 64);
  float a0 = lb[0], a1 = lb[1], a2 = lb[2], a3 = lb[3];
#pragma unroll
  for (int i = 0; i < 16; ++i) {
    float4 v = xp[i];
    a0 += v.x * lw[0][4*i] + v.y * lw[0][4*i+1] + v.z * lw[0][4*i+2] + v.w * lw[0][4*i+3];
    a1 += v.x * lw[1][4*i] + v.y * lw[1][4*i+1] + v.z * lw[1][4*i+2] + v.w * lw[1][4*i+3];
    a2 += v.x * lw[2][4*i] + v.y * lw[2][4*i+1] + v.z * lw[2][4*i+2] + v.w * lw[2][4*i+3];
    a3 += v.x * lw[3][4*i] + v.y * lw[3][4*i+1] + v.z * lw[3][4*i+2] + v.w * lw[3][4*i+3];
  }
  a0 = tanhf(a0) * PI_F; a1 = tanhf(a1) * PI_F;
  a2 = tanhf(a2) * PI_F; a3 = tanhf(a3) * PI_F;
  float p01 = a0 * a1, p12 = a1 * a2, p23 = a2 * a3;

  float dr[16], di[16];
#pragma unroll
  for (int d = 0; d < 16; ++d) {
    float s0 = (d & 8) ? -1.f : 1.f;
    float s1 = (d & 4) ? -1.f : 1.f;
    float s2 = (d & 2) ? -1.f : 1.f;
    float s3 = (d & 1) ? -1.f : 1.f;
    float arg = a0*s0 + a1*s1 + a2*s2 + a3*s3
              + p01*s0*s1 + p12*s1*s2 + p23*s2*s3;
    float sn, cs;
    sincosf(0.5f * arg, &sn, &cs);
    dr[d] = cs; di[d] = -sn;
  }
  float hr[16], hi[16];
#pragma unroll
  for (int i = 0; i < 16; ++i) { hr[i] = dr[i]; hi[i] = di[i]; }
#pragma unroll
  for (int stp = 1; stp < 16; stp <<= 1) {
#pragma unroll
    for (int i = 0; i < 16; ++i) {
      if (!(i & stp)) {
        float xr = hr[i], yr = hr[i + stp];
        hr[i] = xr + yr; hr[i + stp] = xr - yr;
        float xi = hi[i], yi = hi[i + stp];
        hi[i] = xi + yi; hi[i + stp] = xi - yi;
      }
    }
  }
#pragma unroll
  for (int d = 0; d < 16; ++d) {
    st[2*d]   = (dr[d] * hr[d] - di[d] * hi[d]) * 0.0625f;
    st[2*d+1] = (dr[d] * hi[d] + di[d] * hr[d]) * 0.0625f;
  }
}

static __device__ __forceinline__ void pack_store(
    const float st[32], ushort_t* __restrict__ outH,
    ushort_t* __restrict__ outL, size_t rb)
{
  unsigned uh[16], ul[16];
#pragma unroll
  for (int d = 0; d < 16; ++d) {
    ushort_t rh = f2bf(st[2*d]), ih = f2bf(st[2*d+1]);
    ushort_t rl = f2bf(st[2*d]   - bf2f(rh));
    ushort_t il = f2bf(st[2*d+1] - bf2f(ih));
    uh[d] = (unsigned)rh | ((unsigned)ih << 16);
    ul[d] = (unsigned)rl | ((unsigned)il << 16);
  }
  uint4* ph = (uint4*)(outH + rb);
  uint4* pl = (uint4*)(outL + rb);
#pragma unroll
  for (int i = 0; i < 4; ++i) {
    ph[i] = make_uint4(uh[4*i], uh[4*i+1], uh[4*i+2], uh[4*i+3]);
    pl[i] = make_uint4(ul[4*i], ul[4*i+1], ul[4*i+2], ul[4*i+3]);
  }
}

// ---------------------------------------------------------------------------
// k_states2: states as bf16 hi/lo.  [(b*8+h)*1024 + l][32].
// ---------------------------------------------------------------------------
__global__ __launch_bounds__(256) void k_states2(
    const float* __restrict__ x, const float* __restrict__ w,
    const float* __restrict__ bias, ushort_t* __restrict__ outH,
    ushort_t* __restrict__ outL)
{
  __shared__ float lw[4][64];
  __shared__ float lb[4];
  int t = threadIdx.x;
  lw[t >> 6][t & 63] = w[t];
  if (t < 4) lb[t] = bias[t];
  __syncthreads();

  int n = blockIdx.x * 256 + t;
  float st[32];
  state_vec(x, lw, lb, n, st);
  int b = n >> 13, l = (n >> 3) & 1023, h = n & 7;
  pack_store(st, outH, outL, ((size_t)(b * Hq + h) * Lq + l) * 32);
}

// ---------------------------------------------------------------------------
// k_vt: V [B][S][H][64] f32 -> VT [bh][d][s] bf16 (hi only)
// ---------------------------------------------------------------------------
__global__ __launch_bounds__(256) void k_vt(
    const float* __restrict__ v, ushort_t* __restrict__ vtH)
{
  __shared__ float tile[64 * 68];
  int bid = blockIdx.x;
  int bh = bid >> 4, s0 = (bid & 15) << 6;
  int b = bh >> 3, h = bh & 7;
  int t = threadIdx.x;
  int sl = t >> 2, dq = (t & 3) << 4;
  const float4* src = (const float4*)(v + (((size_t)b * Sq + s0 + sl) * Hq + h) * 64 + dq);
#pragma unroll
  for (int i = 0; i < 4; ++i)
    *(float4*)&tile[sl * 68 + dq + 4 * i] = src[i];
  __syncthreads();
  int d = t >> 2, sq = (t & 3) << 4;
  unsigned hw[8];
#pragma unroll
  for (int j = 0; j < 8; ++j) {
    float x0 = tile[(sq + 2*j)     * 68 + d];
    float x1 = tile[(sq + 2*j + 1) * 68 + d];
    hw[j] = (unsigned)f2bf(x0) | ((unsigned)f2bf(x1) << 16);
  }
  size_t ob = ((size_t)bh * 64 + d) * 1024 + s0 + sq;
  uint4* oh = (uint4*)(vtH + ob);
  oh[0] = make_uint4(hw[0], hw[1], hw[2], hw[3]);
  oh[1] = make_uint4(hw[4], hw[5], hw[6], hw[7]);
}

// ---------------------------------------------------------------------------
// k_fidpv: fused normalized-scores + PV context.
// 1024 blocks (bh, 64-row tile), 4 waves x 16 rows, full 1024 s per wave
// -> full PV rows per wave, NO cross-wave reduction, NO block barriers.
// Pass 1: hi-only fid -> rowsum.
// Pass 2 per 64-s chunk:
//   prefetch 8 V fragments (L2) -> split-3 fid -> scale -> wtr (LDS)
//   -> transpose-readback attn stores -> PV: wtr rows as bf16-hi A-frag
//   x V B-frag -> 8 MFMA into acc.
// Epilogue: ctx stores.
// ---------------------------------------------------------------------------
__global__ __launch_bounds__(256) void k_fidpv(
    const ushort_t* __restrict__ QH, const ushort_t* __restrict__ QL,
    const ushort_t* __restrict__ KH, const ushort_t* __restrict__ KL,
    const ushort_t* __restrict__ VTH, float* __restrict__ attn,
    float* __restrict__ ctx)
{
  __shared__ float Wtr[4][16 * 68];

  int bid = blockIdx.x;                 // 1024 (%8==0 -> bijective swizzle)
  int xcd = bid & 7, idx = bid >> 3;
  int bh = (xcd << 3) | (idx >> 4);
  int l0 = (idx & 15) << 6;
  int t = threadIdx.x;
  int wv = t >> 6, lane = t & 63;
  int lh = lane & 15, g = lane >> 4, ko = g << 3;
  int rowbase = l0 + (wv << 4);

  size_t qoff = ((size_t)bh * Lq + rowbase + lh) * 32 + ko;
  short8 qh  = *(const short8*)(QH + qoff);
  short8 ql  = *(const short8*)(QL + qoff);
  short8 qph = primef(qh), qpl = primef(ql);

  const ushort_t* kbh = KH + ((size_t)bh * Sq + lh) * 32 + ko;
  const ushort_t* kbl = KL + ((size_t)bh * Sq + lh) * 32 + ko;
  // V B-fragment base: col d = f2*16 + lh, k-offset = g*8 within s-slice
  const ushort_t* vb0 = VTH + ((size_t)bh * 64 + lh) * Sq + ko;

  f4v zero = {0.f, 0.f, 0.f, 0.f};

  // ---- pass 1: rowsum, hi-only fid ----
  float rsum = 0.f;
  for (int sf = 0; sf < 64; ++sf) {
    short8 kh = *(const short8*)(kbh + sf * 512);
    f4v fr = mfma16(kh, qh, zero);
    f4v fi = mfma16(kh, qph, zero);
#pragma unroll
    for (int r = 0; r < 4; ++r) rsum += fr[r]*fr[r] + fi[r]*fi[r];
  }
  rsum += __shfl_xor(rsum, 16);
  rsum += __shfl_xor(rsum, 32);
  float rinv = 1.f / (rsum + 1e-6f);

  // ---- pass 2: fid -> normalize -> attn store + PV ----
  float* abase = attn + ((size_t)bh * Lq + rowbase) * Sq;
  float* wtr = &Wtr[wv][0];
  f4v acc[4] = {zero, zero, zero, zero};

  for (int c = 0; c < 16; ++c) {
    int coff = c * 2048;                // (c*64)*32 (K rows)
    // V prefetch for this chunk: vb[ks][f2] = VT[d=f2*16+lh][c*64+ks*32+g*8]
    short8 vb[2][4];
#pragma unroll
    for (int ks = 0; ks < 2; ++ks)
#pragma unroll
      for (int f2 = 0; f2 < 4; ++f2)
        vb[ks][f2] = *(const short8*)(vb0 + (size_t)(f2 << 4) * Sq
                                      + (c << 6) + (ks << 5));
#pragma unroll
    for (int f = 0; f < 4; ++f) {
      short8 kh = *(const short8*)(kbh + coff + f * 512);
      short8 kl = *(const short8*)(kbl + coff + f * 512);
      f4v fr = mfma16(kh, qh, zero);
      fr = mfma16(kl, qh, fr);
      fr = mfma16(kh, ql, fr);
      f4v fi = mfma16(kh, qph, zero);
      fi = mfma16(kl, qph, fi);
      fi = mfma16(kh, qpl, fi);
      f4v wv4;
#pragma unroll
      for (int r = 0; r < 4; ++r)
        wv4[r] = (fr[r]*fr[r] + fi[r]*fi[r]) * rinv;
      *(f4v*)&wtr[lh * 68 + (f << 4) + (g << 2)] = wv4;
    }
    // transpose readback -> coalesced attn stores (4 rows x 256 B each)
#pragma unroll
    for (int j = 0; j < 4; ++j) {
      int rowp = (j << 2) + g;
      f4v vv = *(const f4v*)&wtr[rowp * 68 + (lh << 2)];
      *(f4v*)(abase + (size_t)rowp * Sq + (c << 6) + (lh << 2)) = vv;
    }
    // PV: A-frag = wtr[row=lh][ks*32 + g*8 ..], bf16-hi; 2-way LDS alias=free
#pragma unroll
    for (int ks = 0; ks < 2; ++ks) {
      f4v w0 = *(const f4v*)&wtr[lh * 68 + (ks << 5) + ko];
      f4v w1 = *(const f4v*)&wtr[lh * 68 + (ks << 5) + ko + 4];
      short8 wh;
#pragma unroll
      for (int e = 0; e < 4; ++e) wh[e] = (short)f2bf(w0[e]);
#pragma unroll
      for (int e = 0; e < 4; ++e) wh[4 + e] = (short)f2bf(w1[e]);
#pragma unroll
      for (int f2 = 0; f2 < 4; ++f2)
        acc[f2] = mfma16(wh, vb[ks][f2], acc[f2]);
    }
  }

  // ---- epilogue: ctx stores ----
  int b = bh >> 3, h = bh & 7;
#pragma unroll
  for (int f2 = 0; f2 < 4; ++f2) {
    int d = (f2 << 4) + lh;
#pragma unroll
    for (int r = 0; r < 4; ++r) {
      int l = rowbase + (g << 2) + r;
      ctx[(((size_t)b * Lq + l) * Hq + h) * 64 + d] = acc[f2][r];
    }
  }
}

// ===========================================================================
extern "C" void kernel_launch(void* const* d_in, const int* in_sizes, int n_in,
                              void* d_out, int out_size, void* d_ws, size_t ws_size,
                              hipStream_t stream) {
  const float* q  = (const float*)d_in[0];
  const float* k  = (const float*)d_in[1];
  const float* v  = (const float*)d_in[2];
  const float* wq = (const float*)d_in[3];
  const float* bq = (const float*)d_in[4];
  const float* wk = (const float*)d_in[5];
  const float* bk = (const float*)d_in[6];

  float* out  = (float*)d_out;
  float* ctx  = out;                    // [B,L,H,D]  = 4,194,304 floats
  float* attn = out + 4194304;          // [B,H,L,S]  = 67,108,864 floats

  char* wsb = (char*)d_ws;
  ushort_t* QH  = (ushort_t*)(wsb);
  ushort_t* QL  = (ushort_t*)(wsb + (size_t)4  * 1024 * 1024);
  ushort_t* KH  = (ushort_t*)(wsb + (size_t)8  * 1024 * 1024);
  ushort_t* KL  = (ushort_t*)(wsb + (size_t)12 * 1024 * 1024);
  ushort_t* VTH = (ushort_t*)(wsb + (size_t)16 * 1024 * 1024);

  hipLaunchKernelGGL(k_states2, dim3(256), dim3(256), 0, stream, q, wq, bq, QH, QL);
  hipLaunchKernelGGL(k_states2, dim3(256), dim3(256), 0, stream, k, wk, bk, KH, KL);
  hipLaunchKernelGGL(k_vt, dim3(1024), dim3(256), 0, stream, v, VTH);
  hipLaunchKernelGGL(k_fidpv, dim3(1024), dim3(256), 0, stream,
                     QH, QL, KH, KL, VTH, attn, ctx);
}

// Round 10
// 162.974 us; speedup vs baseline: 1.8616x; 1.0431x over previous
//
#include <hip/hip_runtime.h>
#include <math.h>

#define PI_F 3.14159265358979323846f

constexpr int Bq = 8, Lq = 1024, Sq = 1024, Hq = 8, Dq = 64;

typedef short short8 __attribute__((ext_vector_type(8)));
typedef float f4v __attribute__((ext_vector_type(4)));
typedef unsigned short ushort_t;

static __device__ __forceinline__ ushort_t f2bf(float x) {
  union { float f; unsigned u; } v; v.f = x;
  unsigned r = v.u + 0x7fffu + ((v.u >> 16) & 1u);   // RNE
  return (ushort_t)(r >> 16);
}
static __device__ __forceinline__ float bf2f(ushort_t b) {
  union { unsigned u; float f; } v; v.u = ((unsigned)b) << 16;
  return v.f;
}
static __device__ __forceinline__ f4v mfma16(short8 a, short8 b, f4v c) {
  return __builtin_amdgcn_mfma_f32_16x16x32_bf16(a, b, c, 0, 0, 0);
}
// q~' from q~: pairs (re,im) -> (im,-re); bf16 negate = sign-bit flip
static __device__ __forceinline__ short8 primef(short8 q) {
  short8 r;
#pragma unroll
  for (int i = 0; i < 4; ++i) {
    r[2 * i]     = q[2 * i + 1];
    r[2 * i + 1] = (short)(((ushort_t)q[2 * i]) ^ 0x8000u);
  }
  return r;
}

// ---------------------------------------------------------------------------
// state-math: angles -> diag -> WHT -> st[32] interleaved (re,im) f32
// ---------------------------------------------------------------------------
static __device__ __forceinline__ void state_vec(
    const float* __restrict__ x, const float lw[4][64], const float lb[4],
    int n, float st[32])
{
  const float4* xp = (const float4*)(x + (size_t)n * 64);
  float a0 = lb[0], a1 = lb[1], a2 = lb[2], a3 = lb[3];
#pragma unroll
  for (int i = 0; i < 16; ++i) {
    float4 v = xp[i];
    a0 += v.x * lw[0][4*i] + v.y * lw[0][4*i+1] + v.z * lw[0][4*i+2] + v.w * lw[0][4*i+3];
    a1 += v.x * lw[1][4*i] + v.y * lw[1][4*i+1] + v.z * lw[1][4*i+2] + v.w * lw[1][4*i+3];
    a2 += v.x * lw[2][4*i] + v.y * lw[2][4*i+1] + v.z * lw[2][4*i+2] + v.w * lw[2][4*i+3];
    a3 += v.x * lw[3][4*i] + v.y * lw[3][4*i+1] + v.z * lw[3][4*i+2] + v.w * lw[3][4*i+3];
  }
  a0 = tanhf(a0) * PI_F; a1 = tanhf(a1) * PI_F;
  a2 = tanhf(a2) * PI_F; a3 = tanhf(a3) * PI_F;
  float p01 = a0 * a1, p12 = a1 * a2, p23 = a2 * a3;

  float dr[16], di[16];
#pragma unroll
  for (int d = 0; d < 16; ++d) {
    float s0 = (d & 8) ? -1.f : 1.f;
    float s1 = (d & 4) ? -1.f : 1.f;
    float s2 = (d & 2) ? -1.f : 1.f;
    float s3 = (d & 1) ? -1.f : 1.f;
    float arg = a0*s0 + a1*s1 + a2*s2 + a3*s3
              + p01*s0*s1 + p12*s1*s2 + p23*s2*s3;
    float sn, cs;
    sincosf(0.5f * arg, &sn, &cs);
    dr[d] = cs; di[d] = -sn;
  }
  float hr[16], hi[16];
#pragma unroll
  for (int i = 0; i < 16; ++i) { hr[i] = dr[i]; hi[i] = di[i]; }
#pragma unroll
  for (int stp = 1; stp < 16; stp <<= 1) {
#pragma unroll
    for (int i = 0; i < 16; ++i) {
      if (!(i & stp)) {
        float xr = hr[i], yr = hr[i + stp];
        hr[i] = xr + yr; hr[i + stp] = xr - yr;
        float xi = hi[i], yi = hi[i + stp];
        hi[i] = xi + yi; hi[i + stp] = xi - yi;
      }
    }
  }
#pragma unroll
  for (int d = 0; d < 16; ++d) {
    st[2*d]   = (dr[d] * hr[d] - di[d] * hi[d]) * 0.0625f;
    st[2*d+1] = (dr[d] * hi[d] + di[d] * hr[d]) * 0.0625f;
  }
}

static __device__ __forceinline__ void pack_store(
    const float st[32], ushort_t* __restrict__ outH,
    ushort_t* __restrict__ outL, size_t rb)
{
  unsigned uh[16], ul[16];
#pragma unroll
  for (int d = 0; d < 16; ++d) {
    ushort_t rh = f2bf(st[2*d]), ih = f2bf(st[2*d+1]);
    ushort_t rl = f2bf(st[2*d]   - bf2f(rh));
    ushort_t il = f2bf(st[2*d+1] - bf2f(ih));
    uh[d] = (unsigned)rh | ((unsigned)ih << 16);
    ul[d] = (unsigned)rl | ((unsigned)il << 16);
  }
  uint4* ph = (uint4*)(outH + rb);
  uint4* pl = (uint4*)(outL + rb);
#pragma unroll
  for (int i = 0; i < 4; ++i) {
    ph[i] = make_uint4(uh[4*i], uh[4*i+1], uh[4*i+2], uh[4*i+3]);
    pl[i] = make_uint4(ul[4*i], ul[4*i+1], ul[4*i+2], ul[4*i+3]);
  }
}

// ---------------------------------------------------------------------------
// k_states2: states as bf16 hi/lo.  [(b*8+h)*1024 + l][32].
// ---------------------------------------------------------------------------
__global__ __launch_bounds__(256) void k_states2(
    const float* __restrict__ x, const float* __restrict__ w,
    const float* __restrict__ bias, ushort_t* __restrict__ outH,
    ushort_t* __restrict__ outL)
{
  __shared__ float lw[4][64];
  __shared__ float lb[4];
  int t = threadIdx.x;
  lw[t >> 6][t & 63] = w[t];
  if (t < 4) lb[t] = bias[t];
  __syncthreads();

  int n = blockIdx.x * 256 + t;
  float st[32];
  state_vec(x, lw, lb, n, st);
  int b = n >> 13, l = (n >> 3) & 1023, h = n & 7;
  pack_store(st, outH, outL, ((size_t)(b * Hq + h) * Lq + l) * 32);
}

// ---------------------------------------------------------------------------
// k_vt: V [B][S][H][64] f32 -> VT [bh][d][s] bf16 (hi only)
// ---------------------------------------------------------------------------
__global__ __launch_bounds__(256) void k_vt(
    const float* __restrict__ v, ushort_t* __restrict__ vtH)
{
  __shared__ float tile[64 * 68];
  int bid = blockIdx.x;
  int bh = bid >> 4, s0 = (bid & 15) << 6;
  int b = bh >> 3, h = bh & 7;
  int t = threadIdx.x;
  int sl = t >> 2, dq = (t & 3) << 4;
  const float4* src = (const float4*)(v + (((size_t)b * Sq + s0 + sl) * Hq + h) * 64 + dq);
#pragma unroll
  for (int i = 0; i < 4; ++i)
    *(float4*)&tile[sl * 68 + dq + 4 * i] = src[i];
  __syncthreads();
  int d = t >> 2, sq = (t & 3) << 4;
  unsigned hw[8];
#pragma unroll
  for (int j = 0; j < 8; ++j) {
    float x0 = tile[(sq + 2*j)     * 68 + d];
    float x1 = tile[(sq + 2*j + 1) * 68 + d];
    hw[j] = (unsigned)f2bf(x0) | ((unsigned)f2bf(x1) << 16);
  }
  size_t ob = ((size_t)bh * 64 + d) * 1024 + s0 + sq;
  uint4* oh = (uint4*)(vtH + ob);
  oh[0] = make_uint4(hw[0], hw[1], hw[2], hw[3]);
  oh[1] = make_uint4(hw[4], hw[5], hw[6], hw[7]);
}

// ---------------------------------------------------------------------------
// k_fidpv2: fused normalized-scores + PV context, occupancy-capped.
// __launch_bounds__(256,4): <=128 VGPR -> full 4 blocks/CU residency.
// V fragments loaded AFTER the fid f-loop (short live range); their L2
// latency hides under the transpose-readback attn stores.
// ---------------------------------------------------------------------------
__global__ __launch_bounds__(256, 4) void k_fidpv2(
    const ushort_t* __restrict__ QH, const ushort_t* __restrict__ QL,
    const ushort_t* __restrict__ KH, const ushort_t* __restrict__ KL,
    const ushort_t* __restrict__ VTH, float* __restrict__ attn,
    float* __restrict__ ctx)
{
  __shared__ float Wtr[4][16 * 68];

  int bid = blockIdx.x;                 // 1024 (%8==0 -> bijective swizzle)
  int xcd = bid & 7, idx = bid >> 3;
  int bh = (xcd << 3) | (idx >> 4);
  int l0 = (idx & 15) << 6;
  int t = threadIdx.x;
  int wv = t >> 6, lane = t & 63;
  int lh = lane & 15, g = lane >> 4, ko = g << 3;
  int rowbase = l0 + (wv << 4);

  size_t qoff = ((size_t)bh * Lq + rowbase + lh) * 32 + ko;
  short8 qh  = *(const short8*)(QH + qoff);
  short8 ql  = *(const short8*)(QL + qoff);
  short8 qph = primef(qh), qpl = primef(ql);

  const ushort_t* kbh = KH + ((size_t)bh * Sq + lh) * 32 + ko;
  const ushort_t* kbl = KL + ((size_t)bh * Sq + lh) * 32 + ko;
  // V B-fragment base: col d = f2*16 + lh, k-offset = g*8 within s-slice
  const ushort_t* vb0 = VTH + ((size_t)bh * 64 + lh) * Sq + ko;

  f4v zero = {0.f, 0.f, 0.f, 0.f};

  // ---- pass 1: rowsum, hi-only fid ----
  float rsum = 0.f;
  for (int sf = 0; sf < 64; ++sf) {
    short8 kh = *(const short8*)(kbh + sf * 512);
    f4v fr = mfma16(kh, qh, zero);
    f4v fi = mfma16(kh, qph, zero);
#pragma unroll
    for (int r = 0; r < 4; ++r) rsum += fr[r]*fr[r] + fi[r]*fi[r];
  }
  rsum += __shfl_xor(rsum, 16);
  rsum += __shfl_xor(rsum, 32);
  float rinv = 1.f / (rsum + 1e-6f);

  // ---- pass 2: fid -> normalize -> attn store + PV ----
  float* abase = attn + ((size_t)bh * Lq + rowbase) * Sq;
  float* wtr = &Wtr[wv][0];
  f4v acc[4] = {zero, zero, zero, zero};

  for (int c = 0; c < 16; ++c) {
    int coff = c * 2048;                // (c*64)*32 (K rows)
#pragma unroll
    for (int f = 0; f < 4; ++f) {
      short8 kh = *(const short8*)(kbh + coff + f * 512);
      short8 kl = *(const short8*)(kbl + coff + f * 512);
      f4v fr = mfma16(kh, qh, zero);
      fr = mfma16(kl, qh, fr);
      fr = mfma16(kh, ql, fr);
      f4v fi = mfma16(kh, qph, zero);
      fi = mfma16(kl, qph, fi);
      fi = mfma16(kh, qpl, fi);
      f4v wv4;
#pragma unroll
      for (int r = 0; r < 4; ++r)
        wv4[r] = (fr[r]*fr[r] + fi[r]*fi[r]) * rinv;
      *(f4v*)&wtr[lh * 68 + (f << 4) + (g << 2)] = wv4;
    }
    // V loads for this chunk: issued here, consumed after the stores below;
    // the transpose-readback + attn stores cover their L2 latency.
    short8 vb[2][4];
#pragma unroll
    for (int ks = 0; ks < 2; ++ks)
#pragma unroll
      for (int f2 = 0; f2 < 4; ++f2)
        vb[ks][f2] = *(const short8*)(vb0 + (size_t)(f2 << 4) * Sq
                                      + (c << 6) + (ks << 5));
    // transpose readback -> coalesced attn stores (4 rows x 256 B each)
#pragma unroll
    for (int j = 0; j < 4; ++j) {
      int rowp = (j << 2) + g;
      f4v vv = *(const f4v*)&wtr[rowp * 68 + (lh << 2)];
      *(f4v*)(abase + (size_t)rowp * Sq + (c << 6) + (lh << 2)) = vv;
    }
    // PV: A-frag = wtr[row=lh][ks*32 + g*8 ..], bf16-hi; 2-way LDS alias=free
#pragma unroll
    for (int ks = 0; ks < 2; ++ks) {
      f4v w0 = *(const f4v*)&wtr[lh * 68 + (ks << 5) + ko];
      f4v w1 = *(const f4v*)&wtr[lh * 68 + (ks << 5) + ko + 4];
      short8 wh;
#pragma unroll
      for (int e = 0; e < 4; ++e) wh[e] = (short)f2bf(w0[e]);
#pragma unroll
      for (int e = 0; e < 4; ++e) wh[4 + e] = (short)f2bf(w1[e]);
#pragma unroll
      for (int f2 = 0; f2 < 4; ++f2)
        acc[f2] = mfma16(wh, vb[ks][f2], acc[f2]);
    }
  }

  // ---- epilogue: ctx stores ----
  int b = bh >> 3, h = bh & 7;
#pragma unroll
  for (int f2 = 0; f2 < 4; ++f2) {
    int d = (f2 << 4) + lh;
#pragma unroll
    for (int r = 0; r < 4; ++r) {
      int l = rowbase + (g << 2) + r;
      ctx[(((size_t)b * Lq + l) * Hq + h) * 64 + d] = acc[f2][r];
    }
  }
}

// ===========================================================================
extern "C" void kernel_launch(void* const* d_in, const int* in_sizes, int n_in,
                              void* d_out, int out_size, void* d_ws, size_t ws_size,
                              hipStream_t stream) {
  const float* q  = (const float*)d_in[0];
  const float* k  = (const float*)d_in[1];
  const float* v  = (const float*)d_in[2];
  const float* wq = (const float*)d_in[3];
  const float* bq = (const float*)d_in[4];
  const float* wk = (const float*)d_in[5];
  const float* bk = (const float*)d_in[6];

  float* out  = (float*)d_out;
  float* ctx  = out;                    // [B,L,H,D]  = 4,194,304 floats
  float* attn = out + 4194304;          // [B,H,L,S]  = 67,108,864 floats

  char* wsb = (char*)d_ws;
  ushort_t* QH  = (ushort_t*)(wsb);
  ushort_t* QL  = (ushort_t*)(wsb + (size_t)4  * 1024 * 1024);
  ushort_t* KH  = (ushort_t*)(wsb + (size_t)8  * 1024 * 1024);
  ushort_t* KL  = (ushort_t*)(wsb + (size_t)12 * 1024 * 1024);
  ushort_t* VTH = (ushort_t*)(wsb + (size_t)16 * 1024 * 1024);

  hipLaunchKernelGGL(k_states2, dim3(256), dim3(256), 0, stream, q, wq, bq, QH, QL);
  hipLaunchKernelGGL(k_states2, dim3(256), dim3(256), 0, stream, k, wk, bk, KH, KL);
  hipLaunchKernelGGL(k_vt, dim3(1024), dim3(256), 0, stream, v, VTH);
  hipLaunchKernelGGL(k_fidpv2, dim3(1024), dim3(256), 0, stream,
                     QH, QL, KH, KL, VTH, attn, ctx);
}

// Round 11
// 112.097 us; speedup vs baseline: 2.7065x; 1.4539x over previous
//
#include <hip/hip_runtime.h>
#include <math.h>

#define PI_F 3.14159265358979323846f

constexpr int Bq = 8, Lq = 1024, Sq = 1024, Hq = 8, Dq = 64;

typedef short short8 __attribute__((ext_vector_type(8)));
typedef float f4v __attribute__((ext_vector_type(4)));
typedef unsigned short ushort_t;

static __device__ __forceinline__ ushort_t f2bf(float x) {
  union { float f; unsigned u; } v; v.f = x;
  unsigned r = v.u + 0x7fffu + ((v.u >> 16) & 1u);   // RNE
  return (ushort_t)(r >> 16);
}
static __device__ __forceinline__ float bf2f(ushort_t b) {
  union { unsigned u; float f; } v; v.u = ((unsigned)b) << 16;
  return v.f;
}
static __device__ __forceinline__ f4v mfma16(short8 a, short8 b, f4v c) {
  return __builtin_amdgcn_mfma_f32_16x16x32_bf16(a, b, c, 0, 0, 0);
}
// q~' from q~: pairs (re,im) -> (im,-re); bf16 negate = sign-bit flip
static __device__ __forceinline__ short8 primef(short8 q) {
  short8 r;
#pragma unroll
  for (int i = 0; i < 4; ++i) {
    r[2 * i]     = q[2 * i + 1];
    r[2 * i + 1] = (short)(((ushort_t)q[2 * i]) ^ 0x8000u);
  }
  return r;
}

// ---------------------------------------------------------------------------
// state-math: angles -> diag -> WHT -> st[32] interleaved (re,im) f32
// ---------------------------------------------------------------------------
static __device__ __forceinline__ void state_vec(
    const float* __restrict__ x, const float (*lw)[64], const float* lb,
    int n, float st[32])
{
  const float4* xp = (const float4*)(x + (size_t)n * 64);
  float a0 = lb[0], a1 = lb[1], a2 = lb[2], a3 = lb[3];
#pragma unroll
  for (int i = 0; i < 16; ++i) {
    float4 v = xp[i];
    a0 += v.x * lw[0][4*i] + v.y * lw[0][4*i+1] + v.z * lw[0][4*i+2] + v.w * lw[0][4*i+3];
    a1 += v.x * lw[1][4*i] + v.y * lw[1][4*i+1] + v.z * lw[1][4*i+2] + v.w * lw[1][4*i+3];
    a2 += v.x * lw[2][4*i] + v.y * lw[2][4*i+1] + v.z * lw[2][4*i+2] + v.w * lw[2][4*i+3];
    a3 += v.x * lw[3][4*i] + v.y * lw[3][4*i+1] + v.z * lw[3][4*i+2] + v.w * lw[3][4*i+3];
  }
  a0 = tanhf(a0) * PI_F; a1 = tanhf(a1) * PI_F;
  a2 = tanhf(a2) * PI_F; a3 = tanhf(a3) * PI_F;
  float p01 = a0 * a1, p12 = a1 * a2, p23 = a2 * a3;

  float dr[16], di[16];
#pragma unroll
  for (int d = 0; d < 16; ++d) {
    float s0 = (d & 8) ? -1.f : 1.f;
    float s1 = (d & 4) ? -1.f : 1.f;
    float s2 = (d & 2) ? -1.f : 1.f;
    float s3 = (d & 1) ? -1.f : 1.f;
    float arg = a0*s0 + a1*s1 + a2*s2 + a3*s3
              + p01*s0*s1 + p12*s1*s2 + p23*s2*s3;
    float sn, cs;
    sincosf(0.5f * arg, &sn, &cs);
    dr[d] = cs; di[d] = -sn;
  }
  float hr[16], hi[16];
#pragma unroll
  for (int i = 0; i < 16; ++i) { hr[i] = dr[i]; hi[i] = di[i]; }
#pragma unroll
  for (int stp = 1; stp < 16; stp <<= 1) {
#pragma unroll
    for (int i = 0; i < 16; ++i) {
      if (!(i & stp)) {
        float xr = hr[i], yr = hr[i + stp];
        hr[i] = xr + yr; hr[i + stp] = xr - yr;
        float xi = hi[i], yi = hi[i + stp];
        hi[i] = xi + yi; hi[i + stp] = xi - yi;
      }
    }
  }
#pragma unroll
  for (int d = 0; d < 16; ++d) {
    st[2*d]   = (dr[d] * hr[d] - di[d] * hi[d]) * 0.0625f;
    st[2*d+1] = (dr[d] * hi[d] + di[d] * hr[d]) * 0.0625f;
  }
}

// ---------------------------------------------------------------------------
// k_prep: one launch, three roles by block range.
//  [0,256):    Q states, row layout [(bh)*1024+l][32] bf16 hi/lo -> QH/QL
//  [256,512):  K states, MFMA-FRAGMENT layout -> KFH/KFL
//              frag sf = l>>4; lane slot = (g<<4)|(l&15); elems = q~[8g..8g+7]
//  [512,1536): V pack, fragment layout -> VFH (bf16 hi only)
//              [bh][c][ks][f2][lane][8]: lane (lh,g) = V[s=c*64+ks*32+8g+e][d=f2*16+lh]
// ---------------------------------------------------------------------------
__global__ __launch_bounds__(256) void k_prep(
    const float* __restrict__ qin, const float* __restrict__ kin,
    const float* __restrict__ vin,
    const float* __restrict__ wq, const float* __restrict__ bq,
    const float* __restrict__ wk, const float* __restrict__ bk,
    ushort_t* __restrict__ QH, ushort_t* __restrict__ QL,
    ushort_t* __restrict__ KFH, ushort_t* __restrict__ KFL,
    ushort_t* __restrict__ VFH)
{
  __shared__ float smem[64 * 68];
  int blk = blockIdx.x;
  int t = threadIdx.x;

  if (blk < 512) {
    const bool isQ = (blk < 256);
    const float* x    = isQ ? qin : kin;
    const float* w    = isQ ? wq : wk;
    const float* bias = isQ ? bq : bk;
    float (*lw)[64] = (float(*)[64])smem;
    float* lb = smem + 256;
    lw[t >> 6][t & 63] = w[t];
    if (t < 4) lb[t] = bias[t];
    __syncthreads();

    int n = (blk & 255) * 256 + t;
    float st[32];
    state_vec(x, lw, lb, n, st);
    int b = n >> 13, l = (n >> 3) & 1023, h = n & 7;
    int bh = b * 8 + h;

    unsigned hh[16], ll[16];
#pragma unroll
    for (int i = 0; i < 16; ++i) {
      ushort_t h0 = f2bf(st[2*i]), h1 = f2bf(st[2*i+1]);
      ushort_t e0 = f2bf(st[2*i] - bf2f(h0)), e1 = f2bf(st[2*i+1] - bf2f(h1));
      hh[i] = (unsigned)h0 | ((unsigned)h1 << 16);
      ll[i] = (unsigned)e0 | ((unsigned)e1 << 16);
    }
    if (isQ) {
      size_t rb = ((size_t)bh * Lq + l) * 32;
      uint4* ph = (uint4*)(QH + rb);
      uint4* pl = (uint4*)(QL + rb);
#pragma unroll
      for (int i = 0; i < 4; ++i) {
        ph[i] = make_uint4(hh[4*i], hh[4*i+1], hh[4*i+2], hh[4*i+3]);
        pl[i] = make_uint4(ll[4*i], ll[4*i+1], ll[4*i+2], ll[4*i+3]);
      }
    } else {
      int sf = l >> 4, lh = l & 15;
      size_t fb = (size_t)(bh * 64 + sf) * 512;
#pragma unroll
      for (int g = 0; g < 4; ++g) {
        size_t o = fb + (size_t)((g << 4) + lh) * 8;
        *(uint4*)(KFH + o) = make_uint4(hh[4*g], hh[4*g+1], hh[4*g+2], hh[4*g+3]);
        *(uint4*)(KFL + o) = make_uint4(ll[4*g], ll[4*g+1], ll[4*g+2], ll[4*g+3]);
      }
    }
  } else {
    // ---- role V ----
    int blk2 = blk - 512;               // 0..1023
    int bh = blk2 >> 4, c = blk2 & 15;
    int b = bh >> 3, h = bh & 7;
    int s0 = c << 6;
    int sl = t >> 2, dq = (t & 3) << 4;
    const float4* src =
        (const float4*)(vin + (((size_t)b * Sq + s0 + sl) * Hq + h) * 64 + dq);
#pragma unroll
    for (int i = 0; i < 4; ++i)
      *(float4*)&smem[sl * 68 + dq + 4 * i] = src[i];
    __syncthreads();
#pragma unroll
    for (int sidx = 0; sidx < 2; ++sidx) {
      int slot = sidx * 256 + t;        // 0..511
      int ks = slot >> 8, f2 = (slot >> 6) & 3, lane = slot & 63;
      int lh = lane & 15, g = lane >> 4;
      int d = f2 * 16 + lh;
      unsigned w4[4];
#pragma unroll
      for (int e2 = 0; e2 < 4; ++e2) {
        int sl0 = ks * 32 + g * 8 + 2 * e2;
        w4[e2] = (unsigned)f2bf(smem[sl0 * 68 + d])
               | ((unsigned)f2bf(smem[(sl0 + 1) * 68 + d]) << 16);
      }
      size_t off = ((((size_t)(bh * 16 + c) * 2 + ks) * 4 + f2) * 64 + lane) * 8;
      *(uint4*)(VFH + off) = make_uint4(w4[0], w4[1], w4[2], w4[3]);
    }
  }
}

// ---------------------------------------------------------------------------
// k_fidpv3: fused normalized-scores + PV context, fragment-packed operands.
// 1024 blocks (bh, 64-row tile), 4 waves x 16 rows; no block barriers.
// Every K/V load is a fully lane-contiguous 1 KB fragment load.
// ---------------------------------------------------------------------------
__global__ __launch_bounds__(256, 4) void k_fidpv3(
    const ushort_t* __restrict__ QH, const ushort_t* __restrict__ QL,
    const ushort_t* __restrict__ KFH, const ushort_t* __restrict__ KFL,
    const ushort_t* __restrict__ VFH, float* __restrict__ attn,
    float* __restrict__ ctx)
{
  __shared__ float Wtr[4][16 * 68];

  int bid = blockIdx.x;                 // 1024 (%8==0 -> bijective swizzle)
  int xcd = bid & 7, idx = bid >> 3;
  int bh = (xcd << 3) | (idx >> 4);
  int l0 = (idx & 15) << 6;
  int t = threadIdx.x;
  int wv = t >> 6, lane = t & 63;
  int lh = lane & 15, g = lane >> 4, ko = g << 3;
  int rowbase = l0 + (wv << 4);

  size_t qoff = ((size_t)bh * Lq + rowbase + lh) * 32 + ko;
  short8 qh  = *(const short8*)(QH + qoff);
  short8 ql  = *(const short8*)(QL + qoff);
  short8 qph = primef(qh), qpl = primef(ql);

  const ushort_t* kfh = KFH + (size_t)bh * 32768 + (size_t)lane * 8;
  const ushort_t* kfl = KFL + (size_t)bh * 32768 + (size_t)lane * 8;
  const ushort_t* vfb = VFH + (size_t)bh * 65536 + (size_t)lane * 8;

  f4v zero = {0.f, 0.f, 0.f, 0.f};

  // ---- pass 1: rowsum, hi-only fid (sequential fragment stream) ----
  float rsum = 0.f;
#pragma unroll 8
  for (int sf = 0; sf < 64; ++sf) {
    short8 kh = *(const short8*)(kfh + sf * 512);
    f4v fr = mfma16(kh, qh, zero);
    f4v fi = mfma16(kh, qph, zero);
#pragma unroll
    for (int r = 0; r < 4; ++r) rsum += fr[r]*fr[r] + fi[r]*fi[r];
  }
  rsum += __shfl_xor(rsum, 16);
  rsum += __shfl_xor(rsum, 32);
  float rinv = 1.f / (rsum + 1e-6f);

  // ---- pass 2: fid -> normalize -> attn store + PV ----
  float* abase = attn + ((size_t)bh * Lq + rowbase) * Sq;
  float* wtr = &Wtr[wv][0];
  f4v acc[4] = {zero, zero, zero, zero};

  for (int c = 0; c < 16; ++c) {
    // V fragments for this chunk (coalesced); fid f-loop covers their latency
    short8 vb[2][4];
#pragma unroll
    for (int ks = 0; ks < 2; ++ks)
#pragma unroll
      for (int f2 = 0; f2 < 4; ++f2)
        vb[ks][f2] = *(const short8*)(vfb + (size_t)(((c*2+ks)*4+f2)) * 512);

#pragma unroll
    for (int f = 0; f < 4; ++f) {
      int sf = c * 4 + f;
      short8 kh = *(const short8*)(kfh + sf * 512);
      short8 kl = *(const short8*)(kfl + sf * 512);
      f4v fr = mfma16(kh, qh, zero);
      fr = mfma16(kl, qh, fr);
      fr = mfma16(kh, ql, fr);
      f4v fi = mfma16(kh, qph, zero);
      fi = mfma16(kl, qph, fi);
      fi = mfma16(kh, qpl, fi);
      f4v wv4;
#pragma unroll
      for (int r = 0; r < 4; ++r)
        wv4[r] = (fr[r]*fr[r] + fi[r]*fi[r]) * rinv;
      *(f4v*)&wtr[lh * 68 + (f << 4) + (g << 2)] = wv4;
    }
    // transpose readback -> coalesced attn stores (4 rows x 256 B each)
#pragma unroll
    for (int j = 0; j < 4; ++j) {
      int rowp = (j << 2) + g;
      f4v vv = *(const f4v*)&wtr[rowp * 68 + (lh << 2)];
      *(f4v*)(abase + (size_t)rowp * Sq + (c << 6) + (lh << 2)) = vv;
    }
    // PV: A-frag from wtr (2-way LDS alias = free), B-frag = vb
#pragma unroll
    for (int ks = 0; ks < 2; ++ks) {
      f4v w0 = *(const f4v*)&wtr[lh * 68 + (ks << 5) + ko];
      f4v w1 = *(const f4v*)&wtr[lh * 68 + (ks << 5) + ko + 4];
      short8 wh;
#pragma unroll
      for (int e = 0; e < 4; ++e) wh[e] = (short)f2bf(w0[e]);
#pragma unroll
      for (int e = 0; e < 4; ++e) wh[4 + e] = (short)f2bf(w1[e]);
#pragma unroll
      for (int f2 = 0; f2 < 4; ++f2)
        acc[f2] = mfma16(wh, vb[ks][f2], acc[f2]);
    }
  }

  // ---- epilogue: ctx stores ----
  int b = bh >> 3, h = bh & 7;
#pragma unroll
  for (int f2 = 0; f2 < 4; ++f2) {
    int d = (f2 << 4) + lh;
#pragma unroll
    for (int r = 0; r < 4; ++r) {
      int l = rowbase + (g << 2) + r;
      ctx[(((size_t)b * Lq + l) * Hq + h) * 64 + d] = acc[f2][r];
    }
  }
}

// ===========================================================================
extern "C" void kernel_launch(void* const* d_in, const int* in_sizes, int n_in,
                              void* d_out, int out_size, void* d_ws, size_t ws_size,
                              hipStream_t stream) {
  const float* q  = (const float*)d_in[0];
  const float* k  = (const float*)d_in[1];
  const float* v  = (const float*)d_in[2];
  const float* wq = (const float*)d_in[3];
  const float* bq = (const float*)d_in[4];
  const float* wk = (const float*)d_in[5];
  const float* bk = (const float*)d_in[6];

  float* out  = (float*)d_out;
  float* ctx  = out;                    // [B,L,H,D]  = 4,194,304 floats
  float* attn = out + 4194304;          // [B,H,L,S]  = 67,108,864 floats

  char* wsb = (char*)d_ws;
  ushort_t* QH  = (ushort_t*)(wsb);
  ushort_t* QL  = (ushort_t*)(wsb + (size_t)4  * 1024 * 1024);
  ushort_t* KFH = (ushort_t*)(wsb + (size_t)8  * 1024 * 1024);
  ushort_t* KFL = (ushort_t*)(wsb + (size_t)12 * 1024 * 1024);
  ushort_t* VFH = (ushort_t*)(wsb + (size_t)16 * 1024 * 1024);  // 8 MB

  hipLaunchKernelGGL(k_prep, dim3(1536), dim3(256), 0, stream,
                     q, k, v, wq, bq, wk, bk, QH, QL, KFH, KFL, VFH);
  hipLaunchKernelGGL(k_fidpv3, dim3(1024), dim3(256), 0, stream,
                     QH, QL, KFH, KFL, VFH, attn, ctx);
}

// Round 12
// 96.209 us; speedup vs baseline: 3.1535x; 1.1651x over previous
//
#include <hip/hip_runtime.h>
#include <math.h>

#define PI_F 3.14159265358979323846f

constexpr int Bq = 8, Lq = 1024, Sq = 1024, Hq = 8, Dq = 64;

typedef short short8 __attribute__((ext_vector_type(8)));
typedef float f4v __attribute__((ext_vector_type(4)));
typedef unsigned short ushort_t;

static __device__ __forceinline__ ushort_t f2bf(float x) {
  union { float f; unsigned u; } v; v.f = x;
  unsigned r = v.u + 0x7fffu + ((v.u >> 16) & 1u);   // RNE
  return (ushort_t)(r >> 16);
}
static __device__ __forceinline__ float bf2f(ushort_t b) {
  union { unsigned u; float f; } v; v.u = ((unsigned)b) << 16;
  return v.f;
}
static __device__ __forceinline__ f4v mfma16(short8 a, short8 b, f4v c) {
  return __builtin_amdgcn_mfma_f32_16x16x32_bf16(a, b, c, 0, 0, 0);
}
// q~' from q~: pairs (re,im) -> (im,-re); bf16 negate = sign-bit flip
static __device__ __forceinline__ short8 primef(short8 q) {
  short8 r;
#pragma unroll
  for (int i = 0; i < 4; ++i) {
    r[2 * i]     = q[2 * i + 1];
    r[2 * i + 1] = (short)(((ushort_t)q[2 * i]) ^ 0x8000u);
  }
  return r;
}

// ---------------------------------------------------------------------------
// state-math: angles -> diag -> WHT -> st[32] interleaved (re,im) f32
// ---------------------------------------------------------------------------
static __device__ __forceinline__ void state_vec(
    const float* __restrict__ x, const float (*lw)[64], const float* lb,
    int n, float st[32])
{
  const float4* xp = (const float4*)(x + (size_t)n * 64);
  float a0 = lb[0], a1 = lb[1], a2 = lb[2], a3 = lb[3];
#pragma unroll
  for (int i = 0; i < 16; ++i) {
    float4 v = xp[i];
    a0 += v.x * lw[0][4*i] + v.y * lw[0][4*i+1] + v.z * lw[0][4*i+2] + v.w * lw[0][4*i+3];
    a1 += v.x * lw[1][4*i] + v.y * lw[1][4*i+1] + v.z * lw[1][4*i+2] + v.w * lw[1][4*i+3];
    a2 += v.x * lw[2][4*i] + v.y * lw[2][4*i+1] + v.z * lw[2][4*i+2] + v.w * lw[2][4*i+3];
    a3 += v.x * lw[3][4*i] + v.y * lw[3][4*i+1] + v.z * lw[3][4*i+2] + v.w * lw[3][4*i+3];
  }
  a0 = tanhf(a0) * PI_F; a1 = tanhf(a1) * PI_F;
  a2 = tanhf(a2) * PI_F; a3 = tanhf(a3) * PI_F;
  float p01 = a0 * a1, p12 = a1 * a2, p23 = a2 * a3;

  float dr[16], di[16];
#pragma unroll
  for (int d = 0; d < 16; ++d) {
    float s0 = (d & 8) ? -1.f : 1.f;
    float s1 = (d & 4) ? -1.f : 1.f;
    float s2 = (d & 2) ? -1.f : 1.f;
    float s3 = (d & 1) ? -1.f : 1.f;
    float arg = a0*s0 + a1*s1 + a2*s2 + a3*s3
              + p01*s0*s1 + p12*s1*s2 + p23*s2*s3;
    float sn, cs;
    sincosf(0.5f * arg, &sn, &cs);
    dr[d] = cs; di[d] = -sn;
  }
  float hr[16], hi[16];
#pragma unroll
  for (int i = 0; i < 16; ++i) { hr[i] = dr[i]; hi[i] = di[i]; }
#pragma unroll
  for (int stp = 1; stp < 16; stp <<= 1) {
#pragma unroll
    for (int i = 0; i < 16; ++i) {
      if (!(i & stp)) {
        float xr = hr[i], yr = hr[i + stp];
        hr[i] = xr + yr; hr[i + stp] = xr - yr;
        float xi = hi[i], yi = hi[i + stp];
        hi[i] = xi + yi; hi[i + stp] = xi - yi;
      }
    }
  }
#pragma unroll
  for (int d = 0; d < 16; ++d) {
    st[2*d]   = (dr[d] * hr[d] - di[d] * hi[d]) * 0.0625f;
    st[2*d+1] = (dr[d] * hi[d] + di[d] * hr[d]) * 0.0625f;
  }
}

// ---------------------------------------------------------------------------
// k_prep: one launch, three roles by block range.
//  [0,256):    Q states, row layout [(bh)*1024+l][32] bf16 hi/lo -> QH/QL
//  [256,512):  K states, MFMA-FRAGMENT layout -> KFH/KFL
//  [512,1536): V pack, fragment layout -> VFH (bf16 hi only)
// ---------------------------------------------------------------------------
__global__ __launch_bounds__(256) void k_prep(
    const float* __restrict__ qin, const float* __restrict__ kin,
    const float* __restrict__ vin,
    const float* __restrict__ wq, const float* __restrict__ bq,
    const float* __restrict__ wk, const float* __restrict__ bk,
    ushort_t* __restrict__ QH, ushort_t* __restrict__ QL,
    ushort_t* __restrict__ KFH, ushort_t* __restrict__ KFL,
    ushort_t* __restrict__ VFH)
{
  __shared__ float smem[64 * 68];
  int blk = blockIdx.x;
  int t = threadIdx.x;

  if (blk < 512) {
    const bool isQ = (blk < 256);
    const float* x    = isQ ? qin : kin;
    const float* w    = isQ ? wq : wk;
    const float* bias = isQ ? bq : bk;
    float (*lw)[64] = (float(*)[64])smem;
    float* lb = smem + 256;
    lw[t >> 6][t & 63] = w[t];
    if (t < 4) lb[t] = bias[t];
    __syncthreads();

    int n = (blk & 255) * 256 + t;
    float st[32];
    state_vec(x, lw, lb, n, st);
    int b = n >> 13, l = (n >> 3) & 1023, h = n & 7;
    int bh = b * 8 + h;

    unsigned hh[16], ll[16];
#pragma unroll
    for (int i = 0; i < 16; ++i) {
      ushort_t h0 = f2bf(st[2*i]), h1 = f2bf(st[2*i+1]);
      ushort_t e0 = f2bf(st[2*i] - bf2f(h0)), e1 = f2bf(st[2*i+1] - bf2f(h1));
      hh[i] = (unsigned)h0 | ((unsigned)h1 << 16);
      ll[i] = (unsigned)e0 | ((unsigned)e1 << 16);
    }
    if (isQ) {
      size_t rb = ((size_t)bh * Lq + l) * 32;
      uint4* ph = (uint4*)(QH + rb);
      uint4* pl = (uint4*)(QL + rb);
#pragma unroll
      for (int i = 0; i < 4; ++i) {
        ph[i] = make_uint4(hh[4*i], hh[4*i+1], hh[4*i+2], hh[4*i+3]);
        pl[i] = make_uint4(ll[4*i], ll[4*i+1], ll[4*i+2], ll[4*i+3]);
      }
    } else {
      int sf = l >> 4, lh = l & 15;
      size_t fb = (size_t)(bh * 64 + sf) * 512;
#pragma unroll
      for (int g = 0; g < 4; ++g) {
        size_t o = fb + (size_t)((g << 4) + lh) * 8;
        *(uint4*)(KFH + o) = make_uint4(hh[4*g], hh[4*g+1], hh[4*g+2], hh[4*g+3]);
        *(uint4*)(KFL + o) = make_uint4(ll[4*g], ll[4*g+1], ll[4*g+2], ll[4*g+3]);
      }
    }
  } else {
    // ---- role V ----
    int blk2 = blk - 512;               // 0..1023
    int bh = blk2 >> 4, c = blk2 & 15;
    int b = bh >> 3, h = bh & 7;
    int s0 = c << 6;
    int sl = t >> 2, dq = (t & 3) << 4;
    const float4* src =
        (const float4*)(vin + (((size_t)b * Sq + s0 + sl) * Hq + h) * 64 + dq);
#pragma unroll
    for (int i = 0; i < 4; ++i)
      *(float4*)&smem[sl * 68 + dq + 4 * i] = src[i];
    __syncthreads();
#pragma unroll
    for (int sidx = 0; sidx < 2; ++sidx) {
      int slot = sidx * 256 + t;        // 0..511
      int ks = slot >> 8, f2 = (slot >> 6) & 3, lane = slot & 63;
      int lh = lane & 15, g = lane >> 4;
      int d = f2 * 16 + lh;
      unsigned w4[4];
#pragma unroll
      for (int e2 = 0; e2 < 4; ++e2) {
        int sl0 = ks * 32 + g * 8 + 2 * e2;
        w4[e2] = (unsigned)f2bf(smem[sl0 * 68 + d])
               | ((unsigned)f2bf(smem[(sl0 + 1) * 68 + d]) << 16);
      }
      size_t off = ((((size_t)(bh * 16 + c) * 2 + ks) * 4 + f2) * 64 + lane) * 8;
      *(uint4*)(VFH + off) = make_uint4(w4[0], w4[1], w4[2], w4[3]);
    }
  }
}

// ---------------------------------------------------------------------------
// k_fidpv4: fused normalized-scores + PV context, fragment-packed operands.
// vs fidpv3: (1) all 8 K fragments of a chunk hoisted to chunk top (register
// prefetch, pure-compute f-loop); (2) attn stores nontemporal (each store
// instr covers full 128B lines -> streams without RMW, keeps L2 for K/V).
// ---------------------------------------------------------------------------
__global__ __launch_bounds__(256, 4) void k_fidpv4(
    const ushort_t* __restrict__ QH, const ushort_t* __restrict__ QL,
    const ushort_t* __restrict__ KFH, const ushort_t* __restrict__ KFL,
    const ushort_t* __restrict__ VFH, float* __restrict__ attn,
    float* __restrict__ ctx)
{
  __shared__ float Wtr[4][16 * 68];

  int bid = blockIdx.x;                 // 1024 (%8==0 -> bijective swizzle)
  int xcd = bid & 7, idx = bid >> 3;
  int bh = (xcd << 3) | (idx >> 4);
  int l0 = (idx & 15) << 6;
  int t = threadIdx.x;
  int wv = t >> 6, lane = t & 63;
  int lh = lane & 15, g = lane >> 4, ko = g << 3;
  int rowbase = l0 + (wv << 4);

  size_t qoff = ((size_t)bh * Lq + rowbase + lh) * 32 + ko;
  short8 qh  = *(const short8*)(QH + qoff);
  short8 ql  = *(const short8*)(QL + qoff);
  short8 qph = primef(qh), qpl = primef(ql);

  const ushort_t* kfh = KFH + (size_t)bh * 32768 + (size_t)lane * 8;
  const ushort_t* kfl = KFL + (size_t)bh * 32768 + (size_t)lane * 8;
  const ushort_t* vfb = VFH + (size_t)bh * 65536 + (size_t)lane * 8;

  f4v zero = {0.f, 0.f, 0.f, 0.f};

  // ---- pass 1: rowsum, hi-only fid (sequential fragment stream) ----
  float rsum = 0.f;
#pragma unroll 8
  for (int sf = 0; sf < 64; ++sf) {
    short8 kh = *(const short8*)(kfh + sf * 512);
    f4v fr = mfma16(kh, qh, zero);
    f4v fi = mfma16(kh, qph, zero);
#pragma unroll
    for (int r = 0; r < 4; ++r) rsum += fr[r]*fr[r] + fi[r]*fi[r];
  }
  rsum += __shfl_xor(rsum, 16);
  rsum += __shfl_xor(rsum, 32);
  float rinv = 1.f / (rsum + 1e-6f);

  // ---- pass 2: fid -> normalize -> attn store + PV ----
  float* abase = attn + ((size_t)bh * Lq + rowbase) * Sq;
  float* wtr = &Wtr[wv][0];
  f4v acc[4] = {zero, zero, zero, zero};

  for (int c = 0; c < 16; ++c) {
    // K fragments for the whole chunk: hoisted, consumed by the f-loop below
    short8 kh[4], kl[4];
#pragma unroll
    for (int f = 0; f < 4; ++f) {
      kh[f] = *(const short8*)(kfh + (c * 4 + f) * 512);
      kl[f] = *(const short8*)(kfl + (c * 4 + f) * 512);
    }
    // V fragments (consumed at chunk bottom; fid phase covers latency)
    short8 vb[2][4];
#pragma unroll
    for (int ks = 0; ks < 2; ++ks)
#pragma unroll
      for (int f2 = 0; f2 < 4; ++f2)
        vb[ks][f2] = *(const short8*)(vfb + (size_t)(((c*2+ks)*4+f2)) * 512);

#pragma unroll
    for (int f = 0; f < 4; ++f) {
      f4v fr = mfma16(kh[f], qh, zero);
      fr = mfma16(kl[f], qh, fr);
      fr = mfma16(kh[f], ql, fr);
      f4v fi = mfma16(kh[f], qph, zero);
      fi = mfma16(kl[f], qph, fi);
      fi = mfma16(kh[f], qpl, fi);
      f4v wv4;
#pragma unroll
      for (int r = 0; r < 4; ++r)
        wv4[r] = (fr[r]*fr[r] + fi[r]*fi[r]) * rinv;
      *(f4v*)&wtr[lh * 68 + (f << 4) + (g << 2)] = wv4;
    }
    // transpose readback -> nontemporal coalesced attn stores
#pragma unroll
    for (int j = 0; j < 4; ++j) {
      int rowp = (j << 2) + g;
      f4v vv = *(const f4v*)&wtr[rowp * 68 + (lh << 2)];
      __builtin_nontemporal_store(
          vv, (f4v*)(abase + (size_t)rowp * Sq + (c << 6) + (lh << 2)));
    }
    // PV: A-frag from wtr (2-way LDS alias = free), B-frag = vb
#pragma unroll
    for (int ks = 0; ks < 2; ++ks) {
      f4v w0 = *(const f4v*)&wtr[lh * 68 + (ks << 5) + ko];
      f4v w1 = *(const f4v*)&wtr[lh * 68 + (ks << 5) + ko + 4];
      short8 wh;
#pragma unroll
      for (int e = 0; e < 4; ++e) wh[e] = (short)f2bf(w0[e]);
#pragma unroll
      for (int e = 0; e < 4; ++e) wh[4 + e] = (short)f2bf(w1[e]);
#pragma unroll
      for (int f2 = 0; f2 < 4; ++f2)
        acc[f2] = mfma16(wh, vb[ks][f2], acc[f2]);
    }
  }

  // ---- epilogue: ctx stores (plain: 64B segments would RMW under NT) ----
  int b = bh >> 3, h = bh & 7;
#pragma unroll
  for (int f2 = 0; f2 < 4; ++f2) {
    int d = (f2 << 4) + lh;
#pragma unroll
    for (int r = 0; r < 4; ++r) {
      int l = rowbase + (g << 2) + r;
      ctx[(((size_t)b * Lq + l) * Hq + h) * 64 + d] = acc[f2][r];
    }
  }
}

// ===========================================================================
extern "C" void kernel_launch(void* const* d_in, const int* in_sizes, int n_in,
                              void* d_out, int out_size, void* d_ws, size_t ws_size,
                              hipStream_t stream) {
  const float* q  = (const float*)d_in[0];
  const float* k  = (const float*)d_in[1];
  const float* v  = (const float*)d_in[2];
  const float* wq = (const float*)d_in[3];
  const float* bq = (const float*)d_in[4];
  const float* wk = (const float*)d_in[5];
  const float* bk = (const float*)d_in[6];

  float* out  = (float*)d_out;
  float* ctx  = out;                    // [B,L,H,D]  = 4,194,304 floats
  float* attn = out + 4194304;          // [B,H,L,S]  = 67,108,864 floats

  char* wsb = (char*)d_ws;
  ushort_t* QH  = (ushort_t*)(wsb);
  ushort_t* QL  = (ushort_t*)(wsb + (size_t)4  * 1024 * 1024);
  ushort_t* KFH = (ushort_t*)(wsb + (size_t)8  * 1024 * 1024);
  ushort_t* KFL = (ushort_t*)(wsb + (size_t)12 * 1024 * 1024);
  ushort_t* VFH = (ushort_t*)(wsb + (size_t)16 * 1024 * 1024);  // 8 MB

  hipLaunchKernelGGL(k_prep, dim3(1536), dim3(256), 0, stream,
                     q, k, v, wq, bq, wk, bk, QH, QL, KFH, KFL, VFH);
  hipLaunchKernelGGL(k_fidpv4, dim3(1024), dim3(256), 0, stream,
                     QH, QL, KFH, KFL, VFH, attn, ctx);
}